// Round 6
// baseline (207.020 us; speedup 1.0000x reference)
//
#include <hip/hip_runtime.h>

// PolyRPE attention, MI355X gfx950.
// prep (cvt+tr+fp32 RPE table) -> QKV GEMM (128x128, BK=32, 3-buffer gl_lds,
// counted vmcnt(4), T2 swizzle, T1 XCD-chunked grid) -> fused flash attention
// (reg-staged K/V dbuf, fp32 RPE loads, exp2, defer-max, DPP) -> proj GEMM.
//
// Dims: B=16, N=577 (pad 640), C=768, h=12, d=64, K=768, 3C=2304.

using u16 = unsigned short;
using u32 = unsigned int;

typedef __bf16 bf16x8 __attribute__((ext_vector_type(8)));
typedef float f32x4 __attribute__((ext_vector_type(4)));

__device__ inline u16 f2bf(float f) {
    u32 u = __builtin_bit_cast(u32, f);
    u32 r = u + 0x7fffu + ((u >> 16) & 1u);   // RNE
    return (u16)(r >> 16);
}
__device__ inline float bf2f(u16 x) {
    return __builtin_bit_cast(float, (u32)x << 16);
}

__device__ inline f32x4 mfma16(bf16x8 a, bf16x8 b, f32x4 c) {
    return __builtin_amdgcn_mfma_f32_16x16x32_bf16(a, b, c, 0, 0, 0);
}

__device__ inline float fexp2(float x) { return __builtin_amdgcn_exp2f(x); }

// bijective XCD chunk remap (m204): consecutive remapped ids stay on one XCD
__device__ inline int xcd_remap(int bid, int nwg) {
    const int q = nwg >> 3, r = nwg & 7;
    const int xcd = bid & 7, idx = bid >> 3;
    return (xcd < r ? xcd * (q + 1) : r * (q + 1) + (xcd - r) * q) + idx;
}

// 16-lane (DPP-row) reductions.
__device__ inline float dpp_max16(float v) {
    int x;
    x = __builtin_amdgcn_update_dpp(0, __builtin_bit_cast(int, v), 0xB1, 0xF, 0xF, true);
    v = fmaxf(v, __builtin_bit_cast(float, x));
    x = __builtin_amdgcn_update_dpp(0, __builtin_bit_cast(int, v), 0x4E, 0xF, 0xF, true);
    v = fmaxf(v, __builtin_bit_cast(float, x));
    x = __builtin_amdgcn_update_dpp(0, __builtin_bit_cast(int, v), 0x124, 0xF, 0xF, true);
    v = fmaxf(v, __builtin_bit_cast(float, x));
    x = __builtin_amdgcn_update_dpp(0, __builtin_bit_cast(int, v), 0x128, 0xF, 0xF, true);
    v = fmaxf(v, __builtin_bit_cast(float, x));
    return v;
}
__device__ inline float dpp_sum16(float v) {
    int x;
    x = __builtin_amdgcn_update_dpp(0, __builtin_bit_cast(int, v), 0xB1, 0xF, 0xF, true);
    v += __builtin_bit_cast(float, x);
    x = __builtin_amdgcn_update_dpp(0, __builtin_bit_cast(int, v), 0x4E, 0xF, 0xF, true);
    v += __builtin_bit_cast(float, x);
    x = __builtin_amdgcn_update_dpp(0, __builtin_bit_cast(int, v), 0x124, 0xF, 0xF, true);
    v += __builtin_bit_cast(float, x);
    x = __builtin_amdgcn_update_dpp(0, __builtin_bit_cast(int, v), 0x128, 0xF, 0xF, true);
    v += __builtin_bit_cast(float, x);
    return v;
}

#define GLOAD_LDS16(g, l)                                                          \
    __builtin_amdgcn_global_load_lds((const __attribute__((address_space(1))) u32*)(g), \
                                     (__attribute__((address_space(3))) u32*)(l), 16, 0, 0)

#define BAR()    asm volatile("s_barrier" ::: "memory")
#define WAITV4() asm volatile("s_waitcnt vmcnt(4)" ::: "memory")
#define WAITV0() asm volatile("s_waitcnt vmcnt(0)" ::: "memory")

// ---------------- prep: cvt x, transpose weights, fp32 RPE table ------------
// rpe2[h][n][m] = poly_h(L1dist(n,m)) * log2e  (fp32), 0 for CLS row/col and
// pad cols m>=577. n = 0..575 only (row 576 handled by k_attn_last).
__global__ void k_prep(const float* __restrict__ x, const float* __restrict__ Wq,
                       const float* __restrict__ Wp, const float* __restrict__ coef,
                       u16* __restrict__ xb, u16* __restrict__ wqkv,
                       u16* __restrict__ wprj, float* __restrict__ rpe2) {
    const int tid0 = blockIdx.x * blockDim.x + threadIdx.x;
    const int stride = gridDim.x * blockDim.x;
    const int n4 = 9232 * 768 / 4;
    for (int i = tid0; i < n4; i += stride) {
        float4 v = ((const float4*)x)[i];
        ushort4 o;
        o.x = f2bf(v.x); o.y = f2bf(v.y); o.z = f2bf(v.z); o.w = f2bf(v.w);
        ((ushort4*)xb)[i] = o;
    }
    for (int i = tid0; i < 768 * 2304; i += stride) {
        int r = i / 2304, c = i - r * 2304;
        wqkv[(size_t)c * 768 + r] = f2bf(Wq[i]);
    }
    for (int i = tid0; i < 768 * 768; i += stride) {
        int r = i / 768, c = i - r * 768;
        wprj[(size_t)c * 768 + r] = f2bf(Wp[i]);
    }
    const float l2e = 1.4426950408889634f;
    for (int i = tid0; i < 12 * 576 * 640; i += stride) {
        const int h = i / (576 * 640);
        const int rem = i - h * (576 * 640);
        const int n = rem / 640, m = rem - (rem / 640) * 640;
        float v = 0.f;
        if (n >= 1 && m >= 1 && m <= 576) {
            const int qi = (n - 1) / 24, qj = (n - 1) - qi * 24;
            const int ki = (m - 1) / 24, kj = (m - 1) - ki * 24;
            const float d = (float)(abs(qi - ki) + abs(qj - kj));
            const float c0 = coef[h * 4 + 0], c1 = coef[h * 4 + 1],
                        c2 = coef[h * 4 + 2], c3 = coef[h * 4 + 3];
            v = (((c3 * d + c2) * d + c1) * d + c0) * l2e;
        }
        rpe2[i] = v;
    }
}

// ---------------- GEMM helpers (swizzle: chunk' = chunk ^ ((row>>1)&3)) -----
__device__ inline void stageAB(const u16* __restrict__ Ag, const u16* __restrict__ Bg,
                               u16* La, u16* Lb, int t, int w) {
#pragma unroll
    for (int c = 0; c < 2; ++c) {
        const int p = c * 256 + t;
        const int row = p >> 2, ch = p & 3;
        const int src = row * 768 + ((ch ^ ((row >> 1) & 3)) * 8);
        GLOAD_LDS16(Ag + src, La + (size_t)(c * 256 + w * 64) * 8);
        GLOAD_LDS16(Bg + src, Lb + (size_t)(c * 256 + w * 64) * 8);
    }
}
__device__ inline bf16x8 ldfrag32(const u16* base, int row, int slot) {
    return *(const bf16x8*)(base + row * 32 + ((slot ^ ((row >> 1) & 3)) * 8));
}

// GEMM: C[M x N] = A[M x 768] * Bw^T, Bw [N][768] bf16. 128x128 tile, BK=32,
// 4 waves, 3-buffer gl_lds pipeline, vmcnt(4). 1-D grid, T1 XCD chunking,
// n-panel fastest within chunk (A-strip L2 reuse). NB = N/128.
// MODE 0: QKV scatter -> Q/K [bh][640][64], Vt [bh][64][640]; MODE 1: fp32+bias.
template <int MODE, int NB>
__launch_bounds__(256, 3)
__global__ void k_gemm(const u16* __restrict__ A, const u16* __restrict__ Bw,
                       u16* __restrict__ q_out, u16* __restrict__ k_out,
                       u16* __restrict__ v_out,
                       float* __restrict__ f_out, const float* __restrict__ bias) {
    constexpr int NT = 24;                    // 768/32
    constexpr int M = 9232;
    const int wgid = xcd_remap(blockIdx.x, gridDim.x);
    const int mbase = (wgid / NB) * 128;
    const int nbase = (wgid - (wgid / NB) * NB) * 128;
    __shared__ alignas(16) u16 lds[3][2][128 * 32];   // 48 KB
    const int t = threadIdx.x;
    const int lane = t & 63, w = t >> 6;
    const int lr = lane & 15, lg = lane >> 4;
    const int wrow = (w >> 1) * 64, wcol = (w & 1) * 64;
    const u16* Ag = A + (size_t)mbase * 768;
    const u16* Bg = Bw + (size_t)nbase * 768;
    f32x4 acc[4][4] = {};

    stageAB(Ag, Bg, &lds[0][0][0], &lds[0][1][0], t, w);
    stageAB(Ag + 32, Bg + 32, &lds[1][0][0], &lds[1][1][0], t, w);
    WAITV4();           // tile 0 resident; tile 1 in flight
    BAR();

    for (int kt = 0; kt < NT; ++kt) {
        const int cb = kt % 3;
        const u16* Ab = &lds[cb][0][0];
        const u16* Bb = &lds[cb][1][0];
        const bool m2 = (kt + 2) < NT;
        if (m2) {
            const int nb = (kt + 2) % 3;
            stageAB(Ag + (kt + 2) * 32, Bg + (kt + 2) * 32,
                    &lds[nb][0][0], &lds[nb][1][0], t, w);
        }
        bf16x8 af[4], bv[4];
#pragma unroll
        for (int i = 0; i < 4; ++i)
            af[i] = ldfrag32(Ab, wrow + i * 16 + lr, lg);
#pragma unroll
        for (int j = 0; j < 4; ++j)
            bv[j] = ldfrag32(Bb, wcol + j * 16 + lr, lg);
        __builtin_amdgcn_s_setprio(1);
#pragma unroll
        for (int i = 0; i < 4; ++i)
#pragma unroll
            for (int j = 0; j < 4; ++j)
                acc[i][j] = mfma16(af[i], bv[j], acc[i][j]);
        __builtin_amdgcn_s_setprio(0);
        if (kt + 1 < NT) {
            if (m2) { WAITV4(); } else { WAITV0(); }
            BAR();
        }
    }

#pragma unroll
    for (int i = 0; i < 4; ++i) {
#pragma unroll
        for (int j = 0; j < 4; ++j) {
            const int col = nbase + wcol + j * 16 + lr;
#pragma unroll
            for (int r = 0; r < 4; ++r) {
                const int row = mbase + wrow + i * 16 + 4 * lg + r;
                if (row < M) {
                    if (MODE == 0) {
                        const int bb = row / 577;
                        const int nn = row - bb * 577;
                        const int tt = col / 768;
                        const int rem = col - tt * 768;
                        const int hh = rem >> 6, dd = rem & 63;
                        const size_t bh = (size_t)bb * 12 + hh;
                        const u16 val = f2bf(acc[i][j][r]);
                        if (tt == 0)      q_out[(bh * 640 + nn) * 64 + dd] = val;
                        else if (tt == 1) k_out[(bh * 640 + nn) * 64 + dd] = val;
                        else              v_out[(bh * 64 + dd) * 640 + nn] = val;
                    } else {
                        f_out[(size_t)row * 768 + col] = acc[i][j][r] + bias[col];
                    }
                }
            }
        }
    }
}

// ---------------- fused attention (q rows 0..575) ----------------
// K/V tiles reg-staged one tile ahead (T14), double-buffered swizzled LDS.
// RPE from precomputed fp32 table, prefetched per tile before QK^T.
__launch_bounds__(256, 3)
__global__ void k_attn(const u16* __restrict__ Qg, const u16* __restrict__ Kg,
                       const u16* __restrict__ Vtg, const float* __restrict__ rpe2,
                       u16* __restrict__ Og) {
    const int qt = blockIdx.x;          // 0..8
    const int bh = blockIdx.y;          // 0..191 (consecutive blocks share bh)
    const int b = bh / 12, h = bh - b * 12;
    const int t = threadIdx.x;
    const int lane = t & 63, w = t >> 6;
    const int lr = lane & 15, lg = lane >> 4;
    __shared__ alignas(16) u16 Kl[2][4096];
    __shared__ alignas(16) u16 Vl[2][4096];
    __shared__ alignas(16) u16 Plds[4][16 * 72];

    const int qrow0 = qt * 64 + w * 16;
    const u16* qp = Qg + ((size_t)bh * 640 + qrow0 + lr) * 64;
    const bf16x8 qa0 = *(const bf16x8*)(qp + lg * 8);
    const bf16x8 qa1 = *(const bf16x8*)(qp + 32 + lg * 8);

    // per-row RPE base pointers (row n = qrow0 + 4*lg + r)
    const float* rb[4];
#pragma unroll
    for (int r = 0; r < 4; ++r)
        rb[r] = rpe2 + ((size_t)h * 576 + (qrow0 + 4 * lg + r)) * 640;

    float M[4], L[4];
#pragma unroll
    for (int r = 0; r < 4; ++r) { M[r] = -3e38f; L[r] = 0.f; }
    f32x4 acco[4] = {};
    const float scale2 = 0.125f * 1.4426950408889634f;
    const int ch0 = ((lg ^ (lr & 7))) * 8;      // swizzled read chunk (elems)

    const u16* Ksb = Kg + (size_t)bh * 640 * 64;
    const u16* Vsb = Vtg + (size_t)bh * 64 * 640;
    const int pr0 = t >> 3, pc0 = t & 7;
    const int pr1 = (256 + t) >> 3, pc1 = (256 + t) & 7;
    const int kd0 = pr0 * 64 + ((pc0 ^ (pr0 & 7)) * 8);   // swizzled LDS elem offs
    const int kd1 = pr1 * 64 + ((pc1 ^ (pr1 & 7)) * 8);

    {   // prologue: tile 0 -> regs -> LDS buf 0
        uint4 k0 = *(const uint4*)(Ksb + pr0 * 64 + pc0 * 8);
        uint4 k1 = *(const uint4*)(Ksb + pr1 * 64 + pc1 * 8);
        uint4 v0 = *(const uint4*)(Vsb + (size_t)pr0 * 640 + pc0 * 8);
        uint4 v1 = *(const uint4*)(Vsb + (size_t)pr1 * 640 + pc1 * 8);
        *(uint4*)(&Kl[0][kd0]) = k0;
        *(uint4*)(&Kl[0][kd1]) = k1;
        *(uint4*)(&Vl[0][kd0]) = v0;
        *(uint4*)(&Vl[0][kd1]) = v1;
    }
    __syncthreads();
    int cur = 0;

    for (int kt = 0; kt < 10; ++kt) {
        const bool full = (kt < 9);
        uint4 nk0, nk1, nv0, nv1;
        if (full) {     // issue next K/V tile's loads early
            const u16* Ks = Ksb + (size_t)(kt + 1) * 64 * 64;
            const u16* Vs = Vsb + (size_t)(kt + 1) * 64;
            nk0 = *(const uint4*)(Ks + pr0 * 64 + pc0 * 8);
            nk1 = *(const uint4*)(Ks + pr1 * 64 + pc1 * 8);
            nv0 = *(const uint4*)(Vs + (size_t)pr0 * 640 + pc0 * 8);
            nv1 = *(const uint4*)(Vs + (size_t)pr1 * 640 + pc1 * 8);
        }
        // prefetch RPE tile (fp32, L2-resident; hides under QK^T)
        const int mo = kt * 64 + lr;
        float rp[4][4];
#pragma unroll
        for (int cb = 0; cb < 4; ++cb)
#pragma unroll
            for (int r = 0; r < 4; ++r)
                rp[cb][r] = rb[r][mo + cb * 16];

        const u16* Kc = &Kl[cur][0];
        const u16* Vc = &Vl[cur][0];

        // S = Q K^T
        f32x4 sac[4];
#pragma unroll
        for (int cb = 0; cb < 4; ++cb) {
            if (full || cb == 0) {
                const int row = cb * 16 + lr;
                const bf16x8 kb0 = *(const bf16x8*)(Kc + row * 64 + ch0);
                const bf16x8 kb1 = *(const bf16x8*)(Kc + row * 64 + (ch0 ^ 32));
                f32x4 z = {};
                z = mfma16(qa0, kb0, z);
                sac[cb] = mfma16(qa1, kb1, z);
            }
        }

        float s[4][4], tm[4];
#pragma unroll
        for (int r = 0; r < 4; ++r) tm[r] = -3e38f;
#pragma unroll
        for (int cb = 0; cb < 4; ++cb) {
            if (full || cb == 0) {
#pragma unroll
                for (int r = 0; r < 4; ++r) {
                    float v = fmaf(sac[cb][r], scale2, rp[cb][r]);
                    if (!full) v = (lr == 0) ? v : -1e30f;   // pad keys, tail tile
                    s[cb][r] = v;
                    tm[r] = fmaxf(tm[r], v);
                }
            } else {
#pragma unroll
                for (int r = 0; r < 4; ++r) s[cb][r] = -1e30f;
            }
        }
#pragma unroll
        for (int r = 0; r < 4; ++r) tm[r] = dpp_max16(tm[r]);

        float over = tm[0] - M[0];
        over = fmaxf(over, tm[1] - M[1]);
        over = fmaxf(over, tm[2] - M[2]);
        over = fmaxf(over, tm[3] - M[3]);
        if (__any(over > 11.5f)) {
#pragma unroll
            for (int r = 0; r < 4; ++r) {
                const float Mn = fmaxf(M[r], tm[r]);
                const float a = fexp2(M[r] - Mn);
                L[r] *= a;
                acco[0][r] *= a; acco[1][r] *= a;
                acco[2][r] *= a; acco[3][r] *= a;
                M[r] = Mn;
            }
        }

        u16* pw = &Plds[w][0];
#pragma unroll
        for (int cb = 0; cb < 4; ++cb)
#pragma unroll
            for (int r = 0; r < 4; ++r) {
                const float p = fexp2(s[cb][r] - M[r]);
                L[r] += p;
                pw[(4 * lg + r) * 72 + cb * 16 + lr] = f2bf(p);
            }
        const bf16x8 pa0 = *(const bf16x8*)(pw + lr * 72 + lg * 8);
        const bf16x8 pa1 = *(const bf16x8*)(pw + lr * 72 + 32 + lg * 8);
#pragma unroll
        for (int f = 0; f < 4; ++f) {
            const int vrow = f * 16 + lr;
            const bf16x8 vb0 = *(const bf16x8*)(Vc + vrow * 64 + ch0);
            acco[f] = mfma16(pa0, vb0, acco[f]);
            if (full) {
                const bf16x8 vb1 = *(const bf16x8*)(Vc + vrow * 64 + (ch0 ^ 32));
                acco[f] = mfma16(pa1, vb1, acco[f]);
            }
        }

        if (full) {     // land prefetched tile into the other buffer
            __syncthreads();
            *(uint4*)(&Kl[cur ^ 1][kd0]) = nk0;
            *(uint4*)(&Kl[cur ^ 1][kd1]) = nk1;
            *(uint4*)(&Vl[cur ^ 1][kd0]) = nv0;
            *(uint4*)(&Vl[cur ^ 1][kd1]) = nv1;
            __syncthreads();
            cur ^= 1;
        }
    }

    float inv[4];
#pragma unroll
    for (int r = 0; r < 4; ++r) inv[r] = __builtin_amdgcn_rcpf(dpp_sum16(L[r]));
#pragma unroll
    for (int f = 0; f < 4; ++f)
#pragma unroll
        for (int r = 0; r < 4; ++r) {
            const int n = qrow0 + 4 * lg + r;     // <= 575, always valid
            Og[((size_t)b * 577 + n) * 768 + h * 64 + f * 16 + lr] =
                f2bf(acco[f][r] * inv[r]);
        }
}

// ---------------- attention for the single leftover row n=576 ----------------
__launch_bounds__(256)
__global__ void k_attn_last(const u16* __restrict__ Qg, const u16* __restrict__ Kg,
                            const u16* __restrict__ Vtg, const float* __restrict__ coef,
                            u16* __restrict__ Og) {
    const int bh = blockIdx.x;
    const int b = bh / 12, h = bh - b * 12;
    const int t = threadIdx.x;
    const int lane = t & 63, w = t >> 6;
    __shared__ float qs[64];
    __shared__ float ps[640];
    __shared__ float red[4];
    __shared__ float opart[4][64];
    const float l2e = 1.4426950408889634f;
    const float c0 = coef[h * 4 + 0] * l2e, c1 = coef[h * 4 + 1] * l2e,
                c2 = coef[h * 4 + 2] * l2e, c3 = coef[h * 4 + 3] * l2e;
    const float scale2 = 0.125f * l2e;

    if (t < 64) qs[t] = bf2f(Qg[((size_t)bh * 640 + 576) * 64 + t]);
    __syncthreads();

    float sv[3];
#pragma unroll
    for (int u = 0; u < 3; ++u) {
        const int k = t + u * 256;
        float s = -3e38f;
        if (k < 577) {
            const u16* kp = Kg + ((size_t)bh * 640 + k) * 64;
            float acc = 0.f;
            for (int j = 0; j < 64; ++j) acc += qs[j] * bf2f(kp[j]);
            float rv = 0.f;
            if (k >= 1) {
                const int km1 = k - 1;
                const int ki = km1 / 24;
                const float d = fabsf(23.f - (float)ki) + fabsf(23.f - (float)(km1 - ki * 24));
                rv = ((c3 * d + c2) * d + c1) * d + c0;
            }
            s = fmaf(acc, scale2, rv);
        }
        sv[u] = s;
    }
    float v = fmaxf(fmaxf(sv[0], sv[1]), sv[2]);
    v = fmaxf(v, __shfl_xor(v, 1));  v = fmaxf(v, __shfl_xor(v, 2));
    v = fmaxf(v, __shfl_xor(v, 4));  v = fmaxf(v, __shfl_xor(v, 8));
    v = fmaxf(v, __shfl_xor(v, 16)); v = fmaxf(v, __shfl_xor(v, 32));
    if (lane == 0) red[w] = v;
    __syncthreads();
    const float Mx = fmaxf(fmaxf(red[0], red[1]), fmaxf(red[2], red[3]));

    float lsum = 0.f;
#pragma unroll
    for (int u = 0; u < 3; ++u) {
        const int k = t + u * 256;
        const float p = (k < 577) ? fexp2(sv[u] - Mx) : 0.f;
        if (k < 640) ps[k] = p;
        lsum += p;
    }
    lsum += __shfl_xor(lsum, 1);  lsum += __shfl_xor(lsum, 2);
    lsum += __shfl_xor(lsum, 4);  lsum += __shfl_xor(lsum, 8);
    lsum += __shfl_xor(lsum, 16); lsum += __shfl_xor(lsum, 32);
    __syncthreads();
    if (lane == 0) red[w] = lsum;
    __syncthreads();
    const float Lx = red[0] + red[1] + red[2] + red[3];

    const int d = t & 63, qd = t >> 6;
    const u16* vp = Vtg + ((size_t)bh * 64 + d) * 640;
    float o = 0.f;
    for (int k = qd * 160; k < qd * 160 + 160; ++k) o += ps[k] * bf2f(vp[k]);
    opart[qd][d] = o;
    __syncthreads();
    if (t < 64) {
        const float oo = (opart[0][t] + opart[1][t] + opart[2][t] + opart[3][t]) / Lx;
        Og[((size_t)b * 577 + 576) * 768 + h * 64 + t] = f2bf(oo);
    }
}

// ---------------- launch ----------------
extern "C" void kernel_launch(void* const* d_in, const int* in_sizes, int n_in,
                              void* d_out, int out_size, void* d_ws, size_t ws_size,
                              hipStream_t stream) {
    const float* x      = (const float*)d_in[0];
    const float* W_qkv  = (const float*)d_in[1];
    const float* W_proj = (const float*)d_in[2];
    const float* b_proj = (const float*)d_in[3];
    const float* coef   = (const float*)d_in[4];
    float* out = (float*)d_out;
    char* ws = (char*)d_ws;

    // ws layout with lifetime aliasing (total 83.8 MB):
    //   xb  : live k_prep..gemm0   |  Og : live attn..gemm1 (ALIASES xb)
    u16*   xb   = (u16*)(ws + 0);                      // 14,180,352
    u16*   Og   = (u16*)(ws + 0);                      // aliases xb (dead then)
    u16*   wqkv = (u16*)(ws + 14180352);               //  3,538,944 (absorbs Og OOB reads)
    u16*   wprj = (u16*)(ws + 17719296);               //  1,179,648
    float* rpe2 = (float*)(ws + 18898944);             // 17,694,720
    u16*   Qg   = (u16*)(ws + 36593664);               // 15,728,640
    u16*   Kg   = (u16*)(ws + 52322304);               // 15,728,640
    u16*   Vtg  = (u16*)(ws + 68050944);               // 15,728,640 -> end 83,779,584

    hipMemsetAsync(Vtg, 0, 15728640, stream);          // pad keys -> 0

    k_prep<<<2048, 256, 0, stream>>>(x, W_qkv, W_proj, coef, xb, wqkv, wprj, rpe2);

    k_gemm<0, 18><<<18 * 73, 256, 0, stream>>>(xb, wqkv, Qg, Kg, Vtg,
                                               nullptr, nullptr);
    k_attn<<<dim3(9, 192), 256, 0, stream>>>(Qg, Kg, Vtg, rpe2, Og);
    k_attn_last<<<192, 256, 0, stream>>>(Qg, Kg, Vtg, coef, Og);
    k_gemm<1, 6><<<6 * 73, 256, 0, stream>>>(Og, wprj, nullptr, nullptr,
                                             nullptr, out, b_proj);
}

// Round 7
// 184.494 us; speedup vs baseline: 1.1221x; 1.1221x over previous
//
#include <hip/hip_runtime.h>

// PolyRPE attention, MI355X gfx950.
// prep (cvt+tr) -> QKV GEMM (128x256 tile, wave 64x128, BK=32, 3-buffer
// gl_lds, counted vmcnt, T2 swizzle, T1 XCD-chunked grid) -> fused flash
// attention (reg-staged K/V dbuf, LDS LUT RPE, exp2, defer-max, DPP) ->
// proj GEMM (128x128).
//
// Dims: B=16, N=577 (pad 640), C=768, h=12, d=64, K=768, 3C=2304.

using u16 = unsigned short;
using u32 = unsigned int;

typedef __bf16 bf16x8 __attribute__((ext_vector_type(8)));
typedef float f32x4 __attribute__((ext_vector_type(4)));

__device__ inline u16 f2bf(float f) {
    u32 u = __builtin_bit_cast(u32, f);
    u32 r = u + 0x7fffu + ((u >> 16) & 1u);   // RNE
    return (u16)(r >> 16);
}
__device__ inline float bf2f(u16 x) {
    return __builtin_bit_cast(float, (u32)x << 16);
}

__device__ inline f32x4 mfma16(bf16x8 a, bf16x8 b, f32x4 c) {
    return __builtin_amdgcn_mfma_f32_16x16x32_bf16(a, b, c, 0, 0, 0);
}

__device__ inline float fexp2(float x) { return __builtin_amdgcn_exp2f(x); }

// bijective XCD chunk remap (m204)
__device__ inline int xcd_remap(int bid, int nwg) {
    const int q = nwg >> 3, r = nwg & 7;
    const int xcd = bid & 7, idx = bid >> 3;
    return (xcd < r ? xcd * (q + 1) : r * (q + 1) + (xcd - r) * q) + idx;
}

// 16-lane (DPP-row) reductions.
__device__ inline float dpp_max16(float v) {
    int x;
    x = __builtin_amdgcn_update_dpp(0, __builtin_bit_cast(int, v), 0xB1, 0xF, 0xF, true);
    v = fmaxf(v, __builtin_bit_cast(float, x));
    x = __builtin_amdgcn_update_dpp(0, __builtin_bit_cast(int, v), 0x4E, 0xF, 0xF, true);
    v = fmaxf(v, __builtin_bit_cast(float, x));
    x = __builtin_amdgcn_update_dpp(0, __builtin_bit_cast(int, v), 0x124, 0xF, 0xF, true);
    v = fmaxf(v, __builtin_bit_cast(float, x));
    x = __builtin_amdgcn_update_dpp(0, __builtin_bit_cast(int, v), 0x128, 0xF, 0xF, true);
    v = fmaxf(v, __builtin_bit_cast(float, x));
    return v;
}
__device__ inline float dpp_sum16(float v) {
    int x;
    x = __builtin_amdgcn_update_dpp(0, __builtin_bit_cast(int, v), 0xB1, 0xF, 0xF, true);
    v += __builtin_bit_cast(float, x);
    x = __builtin_amdgcn_update_dpp(0, __builtin_bit_cast(int, v), 0x4E, 0xF, 0xF, true);
    v += __builtin_bit_cast(float, x);
    x = __builtin_amdgcn_update_dpp(0, __builtin_bit_cast(int, v), 0x124, 0xF, 0xF, true);
    v += __builtin_bit_cast(float, x);
    x = __builtin_amdgcn_update_dpp(0, __builtin_bit_cast(int, v), 0x128, 0xF, 0xF, true);
    v += __builtin_bit_cast(float, x);
    return v;
}

#define GLOAD_LDS16(g, l)                                                          \
    __builtin_amdgcn_global_load_lds((const __attribute__((address_space(1))) u32*)(g), \
                                     (__attribute__((address_space(3))) u32*)(l), 16, 0, 0)

#define BAR()    asm volatile("s_barrier" ::: "memory")
#define WAITV6() asm volatile("s_waitcnt vmcnt(6)" ::: "memory")
#define WAITV4() asm volatile("s_waitcnt vmcnt(4)" ::: "memory")
#define WAITV0() asm volatile("s_waitcnt vmcnt(0)" ::: "memory")

// ---------------- prep: cvt x -> bf16, transpose both weights ----------------
__global__ void k_prep(const float* __restrict__ x, const float* __restrict__ Wq,
                       const float* __restrict__ Wp, u16* __restrict__ xb,
                       u16* __restrict__ wqkv, u16* __restrict__ wprj) {
    const int tid0 = blockIdx.x * blockDim.x + threadIdx.x;
    const int stride = gridDim.x * blockDim.x;
    const int n4 = 9232 * 768 / 4;
    for (int i = tid0; i < n4; i += stride) {
        float4 v = ((const float4*)x)[i];
        ushort4 o;
        o.x = f2bf(v.x); o.y = f2bf(v.y); o.z = f2bf(v.z); o.w = f2bf(v.w);
        ((ushort4*)xb)[i] = o;
    }
    for (int i = tid0; i < 768 * 2304; i += stride) {
        int r = i / 2304, c = i - r * 2304;
        wqkv[(size_t)c * 768 + r] = f2bf(Wq[i]);
    }
    for (int i = tid0; i < 768 * 768; i += stride) {
        int r = i / 768, c = i - r * 768;
        wprj[(size_t)c * 768 + r] = f2bf(Wp[i]);
    }
}

// ---------------- GEMM (swizzle: chunk' = chunk ^ ((row>>1)&3)) --------------
// LDS buffer: A[128][32] (elems 0..4095) then B[NJ*32][32] (elems 4096..).
template <int NJ>
__device__ inline void stageAB(const u16* __restrict__ Ag, const u16* __restrict__ Bg,
                               u16* L, int t) {
#pragma unroll
    for (int c = 0; c < 2; ++c) {               // A: 128 rows
        const int p = c * 256 + t;
        const int row = p >> 2, ch = p & 3;
        GLOAD_LDS16(Ag + row * 768 + ((ch ^ ((row >> 1) & 3)) * 8), L + p * 8);
    }
#pragma unroll
    for (int c = 0; c < NJ / 2; ++c) {          // B: NJ*32 rows
        const int p = c * 256 + t;
        const int row = p >> 2, ch = p & 3;
        GLOAD_LDS16(Bg + row * 768 + ((ch ^ ((row >> 1) & 3)) * 8),
                    L + 4096 + p * 8);
    }
}
__device__ inline bf16x8 ldfrag32(const u16* base, int row, int slot) {
    return *(const bf16x8*)(base + row * 32 + ((slot ^ ((row >> 1) & 3)) * 8));
}

// C[M x N] = A[M x 768] * Bw^T, Bw [N][768] bf16. Block 128 x (NJ*32), BK=32,
// 4 waves 2x2, wave tile 64 x (NJ*16). 3-buffer gl_lds pipeline, counted vmcnt.
// 1-D grid, T1 XCD chunking, n-panel fastest (A-strip L2 reuse). NB = N-tiles.
// MODE 0: QKV scatter -> Q/K [bh][640][64], Vt [bh][64][640]; MODE 1: fp32+bias.
template <int MODE, int NB, int NJ>
__launch_bounds__(256, NJ == 8 ? 2 : 3)
__global__ void k_gemm(const u16* __restrict__ A, const u16* __restrict__ Bw,
                       u16* __restrict__ q_out, u16* __restrict__ k_out,
                       u16* __restrict__ v_out,
                       float* __restrict__ f_out, const float* __restrict__ bias) {
    constexpr int NT = 24;                    // 768/32
    constexpr int M = 9232;
    constexpr int BN = NJ * 32;
    const int wgid = xcd_remap(blockIdx.x, gridDim.x);
    const int mbase = (wgid / NB) * 128;
    const int nbase = (wgid - (wgid / NB) * NB) * BN;
    __shared__ alignas(16) u16 lds[3][4096 + NJ * 1024];
    const int t = threadIdx.x;
    const int lane = t & 63, w = t >> 6;
    const int lr = lane & 15, lg = lane >> 4;
    const int wrow = (w >> 1) * 64, wcol = (w & 1) * (NJ * 16);
    const u16* Ag = A + (size_t)mbase * 768;
    const u16* Bg = Bw + (size_t)nbase * 768;
    f32x4 acc[4][NJ] = {};

    stageAB<NJ>(Ag, Bg, &lds[0][0], t);
    stageAB<NJ>(Ag + 32, Bg + 32, &lds[1][0], t);
    if (NJ == 8) { WAITV6(); } else { WAITV4(); }   // tile 0 resident
    BAR();

    for (int kt = 0; kt < NT; ++kt) {
        const u16* Lc = &lds[kt % 3][0];
        const bool m2 = (kt + 2) < NT;
        if (m2)
            stageAB<NJ>(Ag + (kt + 2) * 32, Bg + (kt + 2) * 32,
                        &lds[(kt + 2) % 3][0], t);
        bf16x8 af[4], bv[NJ];
#pragma unroll
        for (int i = 0; i < 4; ++i)
            af[i] = ldfrag32(Lc, wrow + i * 16 + lr, lg);
#pragma unroll
        for (int j = 0; j < NJ; ++j)
            bv[j] = ldfrag32(Lc + 4096, wcol + j * 16 + lr, lg);
        __builtin_amdgcn_s_setprio(1);
#pragma unroll
        for (int i = 0; i < 4; ++i)
#pragma unroll
            for (int j = 0; j < NJ; ++j)
                acc[i][j] = mfma16(af[i], bv[j], acc[i][j]);
        __builtin_amdgcn_s_setprio(0);
        if (kt + 1 < NT) {
            if (m2) { if (NJ == 8) { WAITV6(); } else { WAITV4(); } }
            else    { WAITV0(); }
            BAR();
        }
    }

#pragma unroll
    for (int i = 0; i < 4; ++i) {
#pragma unroll
        for (int j = 0; j < NJ; ++j) {
            const int col = nbase + wcol + j * 16 + lr;
#pragma unroll
            for (int r = 0; r < 4; ++r) {
                const int row = mbase + wrow + i * 16 + 4 * lg + r;
                if (row < M) {
                    if (MODE == 0) {
                        const int bb = row / 577;
                        const int nn = row - bb * 577;
                        const int tt = col / 768;
                        const int rem = col - tt * 768;
                        const int hh = rem >> 6, dd = rem & 63;
                        const size_t bh = (size_t)bb * 12 + hh;
                        const u16 val = f2bf(acc[i][j][r]);
                        if (tt == 0)      q_out[(bh * 640 + nn) * 64 + dd] = val;
                        else if (tt == 1) k_out[(bh * 640 + nn) * 64 + dd] = val;
                        else              v_out[(bh * 64 + dd) * 640 + nn] = val;
                    } else {
                        f_out[(size_t)row * 768 + col] = acc[i][j][r] + bias[col];
                    }
                }
            }
        }
    }
}

// ---------------- fused attention (q rows 0..575) ----------------
// K/V tiles reg-staged one tile ahead (T14), double-buffered swizzled LDS.
// RPE via per-head LDS LUT over integer L1 distance (CLS coords -> LUT zeros).
__launch_bounds__(256, 3)
__global__ void k_attn(const u16* __restrict__ Qg, const u16* __restrict__ Kg,
                       const u16* __restrict__ Vtg, const float* __restrict__ coef,
                       u16* __restrict__ Og) {
    const int qt = blockIdx.x;          // 0..8
    const int bh = blockIdx.y;          // 0..191 (consecutive blocks share bh)
    const int b = bh / 12, h = bh - b * 12;
    const int t = threadIdx.x;
    const int lane = t & 63, w = t >> 6;
    const int lr = lane & 15, lg = lane >> 4;
    __shared__ alignas(16) u16 Kl[2][4096];
    __shared__ alignas(16) u16 Vl[2][4096];
    __shared__ alignas(16) u16 Plds[4][16 * 72];
    __shared__ float lut[256];

    {   // LUT: poly(dist)*log2e for dist<=46, else 0 (CLS coords land 47..255)
        const float l2e = 1.4426950408889634f;
        const float c0 = coef[h * 4 + 0] * l2e, c1 = coef[h * 4 + 1] * l2e,
                    c2 = coef[h * 4 + 2] * l2e, c3 = coef[h * 4 + 3] * l2e;
        const float d = (float)t;
        lut[t] = (t <= 46) ? (((c3 * d + c2) * d + c1) * d + c0) : 0.f;
    }

    const int qrow0 = qt * 64 + w * 16;
    const u16* qp = Qg + ((size_t)bh * 640 + qrow0 + lr) * 64;
    const bf16x8 qa0 = *(const bf16x8*)(qp + lg * 8);
    const bf16x8 qa1 = *(const bf16x8*)(qp + 32 + lg * 8);

    float gi[4], gj[4];
#pragma unroll
    for (int r = 0; r < 4; ++r) {
        const int n = qrow0 + 4 * lg + r;
        if (n == 0) { gi[r] = 100.f; gj[r] = 0.f; }
        else {
            const int nm1 = n - 1;
            const int qi = nm1 / 24;
            gi[r] = (float)qi;
            gj[r] = (float)(nm1 - qi * 24);
        }
    }

    float M[4], L[4];
#pragma unroll
    for (int r = 0; r < 4; ++r) { M[r] = -3e38f; L[r] = 0.f; }
    f32x4 acco[4] = {};
    const float scale2 = 0.125f * 1.4426950408889634f;
    const int ch0 = ((lg ^ (lr & 7))) * 8;      // swizzled read chunk (elems)

    const u16* Ksb = Kg + (size_t)bh * 640 * 64;
    const u16* Vsb = Vtg + (size_t)bh * 64 * 640;
    const int pr0 = t >> 3, pc0 = t & 7;
    const int pr1 = (256 + t) >> 3, pc1 = (256 + t) & 7;
    const int kd0 = pr0 * 64 + ((pc0 ^ (pr0 & 7)) * 8);   // swizzled LDS offs
    const int kd1 = pr1 * 64 + ((pc1 ^ (pr1 & 7)) * 8);

    {   // prologue: tile 0 -> regs -> LDS buf 0
        uint4 k0 = *(const uint4*)(Ksb + pr0 * 64 + pc0 * 8);
        uint4 k1 = *(const uint4*)(Ksb + pr1 * 64 + pc1 * 8);
        uint4 v0 = *(const uint4*)(Vsb + (size_t)pr0 * 640 + pc0 * 8);
        uint4 v1 = *(const uint4*)(Vsb + (size_t)pr1 * 640 + pc1 * 8);
        *(uint4*)(&Kl[0][kd0]) = k0;
        *(uint4*)(&Kl[0][kd1]) = k1;
        *(uint4*)(&Vl[0][kd0]) = v0;
        *(uint4*)(&Vl[0][kd1]) = v1;
    }
    __syncthreads();
    int cur = 0;

    for (int kt = 0; kt < 10; ++kt) {
        const bool full = (kt < 9);
        uint4 nk0, nk1, nv0, nv1;
        if (full) {     // issue next K/V tile's loads early
            const u16* Ks = Ksb + (size_t)(kt + 1) * 64 * 64;
            const u16* Vs = Vsb + (size_t)(kt + 1) * 64;
            nk0 = *(const uint4*)(Ks + pr0 * 64 + pc0 * 8);
            nk1 = *(const uint4*)(Ks + pr1 * 64 + pc1 * 8);
            nv0 = *(const uint4*)(Vs + (size_t)pr0 * 640 + pc0 * 8);
            nv1 = *(const uint4*)(Vs + (size_t)pr1 * 640 + pc1 * 8);
        }
        const u16* Kc = &Kl[cur][0];
        const u16* Vc = &Vl[cur][0];

        // S = Q K^T
        f32x4 sac[4];
#pragma unroll
        for (int cb = 0; cb < 4; ++cb) {
            if (full || cb == 0) {
                const int row = cb * 16 + lr;
                const bf16x8 kb0 = *(const bf16x8*)(Kc + row * 64 + ch0);
                const bf16x8 kb1 = *(const bf16x8*)(Kc + row * 64 + (ch0 ^ 32));
                f32x4 z = {};
                z = mfma16(qa0, kb0, z);
                sac[cb] = mfma16(qa1, kb1, z);
            }
        }

        float s[4][4], tm[4];
#pragma unroll
        for (int r = 0; r < 4; ++r) tm[r] = -3e38f;
#pragma unroll
        for (int cb = 0; cb < 4; ++cb) {
            if (full || cb == 0) {
                const int m = kt * 64 + cb * 16 + lr;
                float ci, cj;
                if (m == 0) { ci = 200.f; cj = 0.f; }
                else {
                    const int mm1 = m - 1;
                    const int pi = mm1 / 24;
                    ci = (float)pi;
                    cj = (float)(mm1 - pi * 24);
                }
#pragma unroll
                for (int r = 0; r < 4; ++r) {
                    const float df = fabsf(gi[r] - ci) + fabsf(gj[r] - cj);
                    const int idx = (int)df;
                    float v = fmaf(sac[cb][r], scale2, lut[idx]);
                    if (!full) v = (lr == 0) ? v : -1e30f;   // pad keys, tail
                    s[cb][r] = v;
                    tm[r] = fmaxf(tm[r], v);
                }
            } else {
#pragma unroll
                for (int r = 0; r < 4; ++r) s[cb][r] = -1e30f;
            }
        }
#pragma unroll
        for (int r = 0; r < 4; ++r) tm[r] = dpp_max16(tm[r]);

        float over = tm[0] - M[0];
        over = fmaxf(over, tm[1] - M[1]);
        over = fmaxf(over, tm[2] - M[2]);
        over = fmaxf(over, tm[3] - M[3]);
        if (__any(over > 11.5f)) {
#pragma unroll
            for (int r = 0; r < 4; ++r) {
                const float Mn = fmaxf(M[r], tm[r]);
                const float a = fexp2(M[r] - Mn);
                L[r] *= a;
                acco[0][r] *= a; acco[1][r] *= a;
                acco[2][r] *= a; acco[3][r] *= a;
                M[r] = Mn;
            }
        }

        u16* pw = &Plds[w][0];
#pragma unroll
        for (int cb = 0; cb < 4; ++cb)
#pragma unroll
            for (int r = 0; r < 4; ++r) {
                const float p = fexp2(s[cb][r] - M[r]);
                L[r] += p;
                pw[(4 * lg + r) * 72 + cb * 16 + lr] = f2bf(p);
            }
        const bf16x8 pa0 = *(const bf16x8*)(pw + lr * 72 + lg * 8);
        const bf16x8 pa1 = *(const bf16x8*)(pw + lr * 72 + 32 + lg * 8);
#pragma unroll
        for (int f = 0; f < 4; ++f) {
            const int vrow = f * 16 + lr;
            const bf16x8 vb0 = *(const bf16x8*)(Vc + vrow * 64 + ch0);
            acco[f] = mfma16(pa0, vb0, acco[f]);
            if (full) {
                const bf16x8 vb1 = *(const bf16x8*)(Vc + vrow * 64 + (ch0 ^ 32));
                acco[f] = mfma16(pa1, vb1, acco[f]);
            }
        }

        if (full) {     // land prefetched tile into the other buffer
            __syncthreads();
            *(uint4*)(&Kl[cur ^ 1][kd0]) = nk0;
            *(uint4*)(&Kl[cur ^ 1][kd1]) = nk1;
            *(uint4*)(&Vl[cur ^ 1][kd0]) = nv0;
            *(uint4*)(&Vl[cur ^ 1][kd1]) = nv1;
            __syncthreads();
            cur ^= 1;
        }
    }

    float inv[4];
#pragma unroll
    for (int r = 0; r < 4; ++r) inv[r] = __builtin_amdgcn_rcpf(dpp_sum16(L[r]));
#pragma unroll
    for (int f = 0; f < 4; ++f)
#pragma unroll
        for (int r = 0; r < 4; ++r) {
            const int n = qrow0 + 4 * lg + r;     // <= 575, always valid
            Og[((size_t)b * 577 + n) * 768 + h * 64 + f * 16 + lr] =
                f2bf(acco[f][r] * inv[r]);
        }
}

// ---------------- attention for the single leftover row n=576 ----------------
__launch_bounds__(256)
__global__ void k_attn_last(const u16* __restrict__ Qg, const u16* __restrict__ Kg,
                            const u16* __restrict__ Vtg, const float* __restrict__ coef,
                            u16* __restrict__ Og) {
    const int bh = blockIdx.x;
    const int b = bh / 12, h = bh - b * 12;
    const int t = threadIdx.x;
    const int lane = t & 63, w = t >> 6;
    __shared__ float qs[64];
    __shared__ float ps[640];
    __shared__ float red[4];
    __shared__ float opart[4][64];
    const float l2e = 1.4426950408889634f;
    const float c0 = coef[h * 4 + 0] * l2e, c1 = coef[h * 4 + 1] * l2e,
                c2 = coef[h * 4 + 2] * l2e, c3 = coef[h * 4 + 3] * l2e;
    const float scale2 = 0.125f * l2e;

    if (t < 64) qs[t] = bf2f(Qg[((size_t)bh * 640 + 576) * 64 + t]);
    __syncthreads();

    float sv[3];
#pragma unroll
    for (int u = 0; u < 3; ++u) {
        const int k = t + u * 256;
        float s = -3e38f;
        if (k < 577) {
            const u16* kp = Kg + ((size_t)bh * 640 + k) * 64;
            float acc = 0.f;
            for (int j = 0; j < 64; ++j) acc += qs[j] * bf2f(kp[j]);
            float rv = 0.f;
            if (k >= 1) {
                const int km1 = k - 1;
                const int ki = km1 / 24;
                const float d = fabsf(23.f - (float)ki) + fabsf(23.f - (float)(km1 - ki * 24));
                rv = ((c3 * d + c2) * d + c1) * d + c0;
            }
            s = fmaf(acc, scale2, rv);
        }
        sv[u] = s;
    }
    float v = fmaxf(fmaxf(sv[0], sv[1]), sv[2]);
    v = fmaxf(v, __shfl_xor(v, 1));  v = fmaxf(v, __shfl_xor(v, 2));
    v = fmaxf(v, __shfl_xor(v, 4));  v = fmaxf(v, __shfl_xor(v, 8));
    v = fmaxf(v, __shfl_xor(v, 16)); v = fmaxf(v, __shfl_xor(v, 32));
    if (lane == 0) red[w] = v;
    __syncthreads();
    const float Mx = fmaxf(fmaxf(red[0], red[1]), fmaxf(red[2], red[3]));

    float lsum = 0.f;
#pragma unroll
    for (int u = 0; u < 3; ++u) {
        const int k = t + u * 256;
        const float p = (k < 577) ? fexp2(sv[u] - Mx) : 0.f;
        if (k < 640) ps[k] = p;
        lsum += p;
    }
    lsum += __shfl_xor(lsum, 1);  lsum += __shfl_xor(lsum, 2);
    lsum += __shfl_xor(lsum, 4);  lsum += __shfl_xor(lsum, 8);
    lsum += __shfl_xor(lsum, 16); lsum += __shfl_xor(lsum, 32);
    __syncthreads();
    if (lane == 0) red[w] = lsum;
    __syncthreads();
    const float Lx = red[0] + red[1] + red[2] + red[3];

    const int d = t & 63, qd = t >> 6;
    const u16* vp = Vtg + ((size_t)bh * 64 + d) * 640;
    float o = 0.f;
    for (int k = qd * 160; k < qd * 160 + 160; ++k) o += ps[k] * bf2f(vp[k]);
    opart[qd][d] = o;
    __syncthreads();
    if (t < 64) {
        const float oo = (opart[0][t] + opart[1][t] + opart[2][t] + opart[3][t]) / Lx;
        Og[((size_t)b * 577 + 576) * 768 + h * 64 + t] = f2bf(oo);
    }
}

// ---------------- launch ----------------
extern "C" void kernel_launch(void* const* d_in, const int* in_sizes, int n_in,
                              void* d_out, int out_size, void* d_ws, size_t ws_size,
                              hipStream_t stream) {
    const float* x      = (const float*)d_in[0];
    const float* W_qkv  = (const float*)d_in[1];
    const float* W_proj = (const float*)d_in[2];
    const float* b_proj = (const float*)d_in[3];
    const float* coef   = (const float*)d_in[4];
    float* out = (float*)d_out;
    char* ws = (char*)d_ws;

    // ws layout with lifetime aliasing (66.1 MB total):
    //   xb : live prep..gemm0  |  Og : live attn..gemm1 (ALIASES xb)
    u16* xb   = (u16*)(ws + 0);                        // 14,180,352
    u16* Og   = (u16*)(ws + 0);                        // aliases xb
    u16* wqkv = (u16*)(ws + 14180352);                 //  3,538,944 (absorbs OOB)
    u16* wprj = (u16*)(ws + 17719296);                 //  1,179,648
    u16* Qg   = (u16*)(ws + 18898944);                 // 15,728,640
    u16* Kg   = (u16*)(ws + 34627584);                 // 15,728,640
    u16* Vtg  = (u16*)(ws + 50356224);                 // 15,728,640 -> 66,084,864
    // NOTE: no Vtg memset needed — pad keys (577..639) get P = exp2(-1e30-M)=0
    // exactly, and 0 * (any finite bf16 incl. 0xAA poison) = 0.

    k_prep<<<2048, 256, 0, stream>>>(x, W_qkv, W_proj, xb, wqkv, wprj);

    k_gemm<0, 9, 8><<<9 * 73, 256, 0, stream>>>(xb, wqkv, Qg, Kg, Vtg,
                                                nullptr, nullptr);
    k_attn<<<dim3(9, 192), 256, 0, stream>>>(Qg, Kg, Vtg, coef, Og);
    k_attn_last<<<192, 256, 0, stream>>>(Qg, Kg, Vtg, coef, Og);
    k_gemm<1, 6, 4><<<6 * 73, 256, 0, stream>>>(Og, wprj, nullptr, nullptr,
                                                nullptr, out, b_proj);
}

// Round 8
// 183.693 us; speedup vs baseline: 1.1270x; 1.0044x over previous
//
#include <hip/hip_runtime.h>

// PolyRPE attention, MI355X gfx950.
// prep (cvt+tr) -> QKV GEMM (128x128, BK=32, 4-buffer gl_lds pipeline,
// prefetch distance 3, counted vmcnt(8), T2 swizzle, T1 XCD grid) ->
// fused flash attention (reg-staged K/V dbuf, 1 barrier/tile, LDS LUT RPE,
// exp2, defer-max, DPP) -> proj GEMM (same pipeline).
//
// Dims: B=16, N=577 (pad 640), C=768, h=12, d=64, K=768, 3C=2304.

using u16 = unsigned short;
using u32 = unsigned int;

typedef __bf16 bf16x8 __attribute__((ext_vector_type(8)));
typedef float f32x4 __attribute__((ext_vector_type(4)));

__device__ inline u16 f2bf(float f) {
    u32 u = __builtin_bit_cast(u32, f);
    u32 r = u + 0x7fffu + ((u >> 16) & 1u);   // RNE
    return (u16)(r >> 16);
}
__device__ inline float bf2f(u16 x) {
    return __builtin_bit_cast(float, (u32)x << 16);
}

__device__ inline f32x4 mfma16(bf16x8 a, bf16x8 b, f32x4 c) {
    return __builtin_amdgcn_mfma_f32_16x16x32_bf16(a, b, c, 0, 0, 0);
}

__device__ inline float fexp2(float x) { return __builtin_amdgcn_exp2f(x); }

// bijective XCD chunk remap (m204)
__device__ inline int xcd_remap(int bid, int nwg) {
    const int q = nwg >> 3, r = nwg & 7;
    const int xcd = bid & 7, idx = bid >> 3;
    return (xcd < r ? xcd * (q + 1) : r * (q + 1) + (xcd - r) * q) + idx;
}

// 16-lane (DPP-row) reductions.
__device__ inline float dpp_max16(float v) {
    int x;
    x = __builtin_amdgcn_update_dpp(0, __builtin_bit_cast(int, v), 0xB1, 0xF, 0xF, true);
    v = fmaxf(v, __builtin_bit_cast(float, x));
    x = __builtin_amdgcn_update_dpp(0, __builtin_bit_cast(int, v), 0x4E, 0xF, 0xF, true);
    v = fmaxf(v, __builtin_bit_cast(float, x));
    x = __builtin_amdgcn_update_dpp(0, __builtin_bit_cast(int, v), 0x124, 0xF, 0xF, true);
    v = fmaxf(v, __builtin_bit_cast(float, x));
    x = __builtin_amdgcn_update_dpp(0, __builtin_bit_cast(int, v), 0x128, 0xF, 0xF, true);
    v = fmaxf(v, __builtin_bit_cast(float, x));
    return v;
}
__device__ inline float dpp_sum16(float v) {
    int x;
    x = __builtin_amdgcn_update_dpp(0, __builtin_bit_cast(int, v), 0xB1, 0xF, 0xF, true);
    v += __builtin_bit_cast(float, x);
    x = __builtin_amdgcn_update_dpp(0, __builtin_bit_cast(int, v), 0x4E, 0xF, 0xF, true);
    v += __builtin_bit_cast(float, x);
    x = __builtin_amdgcn_update_dpp(0, __builtin_bit_cast(int, v), 0x124, 0xF, 0xF, true);
    v += __builtin_bit_cast(float, x);
    x = __builtin_amdgcn_update_dpp(0, __builtin_bit_cast(int, v), 0x128, 0xF, 0xF, true);
    v += __builtin_bit_cast(float, x);
    return v;
}

#define GLOAD_LDS16(g, l)                                                          \
    __builtin_amdgcn_global_load_lds((const __attribute__((address_space(1))) u32*)(g), \
                                     (__attribute__((address_space(3))) u32*)(l), 16, 0, 0)

#define BAR()    asm volatile("s_barrier" ::: "memory")
#define WAITV8() asm volatile("s_waitcnt vmcnt(8)" ::: "memory")
#define WAITV4() asm volatile("s_waitcnt vmcnt(4)" ::: "memory")
#define WAITV0() asm volatile("s_waitcnt vmcnt(0)" ::: "memory")

// ---------------- prep: cvt x -> bf16, transpose both weights ----------------
__global__ void k_prep(const float* __restrict__ x, const float* __restrict__ Wq,
                       const float* __restrict__ Wp, u16* __restrict__ xb,
                       u16* __restrict__ wqkv, u16* __restrict__ wprj) {
    const int tid0 = blockIdx.x * blockDim.x + threadIdx.x;
    const int stride = gridDim.x * blockDim.x;
    const int n4 = 9232 * 768 / 4;
    for (int i = tid0; i < n4; i += stride) {
        float4 v = ((const float4*)x)[i];
        ushort4 o;
        o.x = f2bf(v.x); o.y = f2bf(v.y); o.z = f2bf(v.z); o.w = f2bf(v.w);
        ((ushort4*)xb)[i] = o;
    }
    for (int i = tid0; i < 768 * 2304; i += stride) {
        int r = i / 2304, c = i - r * 2304;
        wqkv[(size_t)c * 768 + r] = f2bf(Wq[i]);
    }
    for (int i = tid0; i < 768 * 768; i += stride) {
        int r = i / 768, c = i - r * 768;
        wprj[(size_t)c * 768 + r] = f2bf(Wp[i]);
    }
}

// ---------------- GEMM (swizzle: chunk' = chunk ^ ((row>>1)&3)) --------------
// Buffer: A[128][32] (elems 0..4095) then B[128][32] (elems 4096..8191).
__device__ inline void stageAB(const u16* __restrict__ Ag, const u16* __restrict__ Bg,
                               u16* L, int t) {
#pragma unroll
    for (int c = 0; c < 2; ++c) {
        const int p = c * 256 + t;
        const int row = p >> 2, ch = p & 3;
        const int src = row * 768 + ((ch ^ ((row >> 1) & 3)) * 8);
        GLOAD_LDS16(Ag + src, L + p * 8);
        GLOAD_LDS16(Bg + src, L + 4096 + p * 8);
    }
}
__device__ inline bf16x8 ldfrag32(const u16* base, int row, int slot) {
    return *(const bf16x8*)(base + row * 32 + ((slot ^ ((row >> 1) & 3)) * 8));
}

// C[M x N] = A[M x 768] * Bw^T, Bw [N][768] bf16. 128x128 tile, BK=32,
// 4 waves 2x2, 4-buffer gl_lds pipeline, prefetch distance 3, vmcnt(8).
// 1-D grid, T1 XCD chunking, n-panel fastest (A-strip L2 reuse). NB = N-tiles.
// MODE 0: QKV scatter -> Q/K [bh][640][64], Vt [bh][64][640]; MODE 1: fp32+bias.
template <int MODE, int NB>
__launch_bounds__(256, 2)
__global__ void k_gemm(const u16* __restrict__ A, const u16* __restrict__ Bw,
                       u16* __restrict__ q_out, u16* __restrict__ k_out,
                       u16* __restrict__ v_out,
                       float* __restrict__ f_out, const float* __restrict__ bias) {
    constexpr int NT = 24;                    // 768/32
    constexpr int M = 9232;
    const int wgid = xcd_remap(blockIdx.x, gridDim.x);
    const int mbase = (wgid / NB) * 128;
    const int nbase = (wgid - (wgid / NB) * NB) * 128;
    __shared__ alignas(16) u16 lds[4][8192];  // 64 KB -> 2 blocks/CU
    const int t = threadIdx.x;
    const int lane = t & 63, w = t >> 6;
    const int lr = lane & 15, lg = lane >> 4;
    const int wrow = (w >> 1) * 64, wcol = (w & 1) * 64;
    const u16* Ag = A + (size_t)mbase * 768;
    const u16* Bg = Bw + (size_t)nbase * 768;
    f32x4 acc[4][4] = {};

    stageAB(Ag, Bg, &lds[0][0], t);
    stageAB(Ag + 32, Bg + 32, &lds[1][0], t);
    stageAB(Ag + 64, Bg + 64, &lds[2][0], t);
    WAITV8();           // tile 0 resident; tiles 1,2 in flight
    BAR();

    for (int kt = 0; kt < NT; ++kt) {
        const u16* Lc = &lds[kt & 3][0];
        if (kt + 3 < NT)
            stageAB(Ag + (kt + 3) * 32, Bg + (kt + 3) * 32, &lds[(kt + 3) & 3][0], t);
        bf16x8 af[4], bv[4];
#pragma unroll
        for (int i = 0; i < 4; ++i)
            af[i] = ldfrag32(Lc, wrow + i * 16 + lr, lg);
#pragma unroll
        for (int j = 0; j < 4; ++j)
            bv[j] = ldfrag32(Lc + 4096, wcol + j * 16 + lr, lg);
        __builtin_amdgcn_s_setprio(1);
#pragma unroll
        for (int i = 0; i < 4; ++i)
#pragma unroll
            for (int j = 0; j < 4; ++j)
                acc[i][j] = mfma16(af[i], bv[j], acc[i][j]);
        __builtin_amdgcn_s_setprio(0);
        if (kt + 1 < NT) {
            if (kt < NT - 3)       { WAITV8(); }   // tiles kt+2,kt+3 in flight
            else if (kt == NT - 3) { WAITV4(); }   // tile kt+2 in flight
            else                   { WAITV0(); }   // nothing left
            BAR();
        }
    }

#pragma unroll
    for (int i = 0; i < 4; ++i) {
#pragma unroll
        for (int j = 0; j < 4; ++j) {
            const int col = nbase + wcol + j * 16 + lr;
#pragma unroll
            for (int r = 0; r < 4; ++r) {
                const int row = mbase + wrow + i * 16 + 4 * lg + r;
                if (row < M) {
                    if (MODE == 0) {
                        const int bb = row / 577;
                        const int nn = row - bb * 577;
                        const int tt = col / 768;
                        const int rem = col - tt * 768;
                        const int hh = rem >> 6, dd = rem & 63;
                        const size_t bh = (size_t)bb * 12 + hh;
                        const u16 val = f2bf(acc[i][j][r]);
                        if (tt == 0)      q_out[(bh * 640 + nn) * 64 + dd] = val;
                        else if (tt == 1) k_out[(bh * 640 + nn) * 64 + dd] = val;
                        else              v_out[(bh * 64 + dd) * 640 + nn] = val;
                    } else {
                        f_out[(size_t)row * 768 + col] = acc[i][j][r] + bias[col];
                    }
                }
            }
        }
    }
}

// ---------------- fused attention (q rows 0..575) ----------------
// K/V tiles reg-staged one tile ahead (T14), double-buffered swizzled LDS,
// ONE barrier per tile (stores go to the buffer no wave reads this iter).
__launch_bounds__(256, 3)
__global__ void k_attn(const u16* __restrict__ Qg, const u16* __restrict__ Kg,
                       const u16* __restrict__ Vtg, const float* __restrict__ coef,
                       u16* __restrict__ Og) {
    const int qt = blockIdx.x;          // 0..8
    const int bh = blockIdx.y;          // 0..191 (consecutive blocks share bh)
    const int b = bh / 12, h = bh - b * 12;
    const int t = threadIdx.x;
    const int lane = t & 63, w = t >> 6;
    const int lr = lane & 15, lg = lane >> 4;
    __shared__ alignas(16) u16 Kl[2][4096];
    __shared__ alignas(16) u16 Vl[2][4096];
    __shared__ alignas(16) u16 Plds[4][16 * 72];
    __shared__ float lut[256];

    {   // LUT: poly(dist)*log2e for dist<=46, else 0 (CLS coords land 47..255)
        const float l2e = 1.4426950408889634f;
        const float c0 = coef[h * 4 + 0] * l2e, c1 = coef[h * 4 + 1] * l2e,
                    c2 = coef[h * 4 + 2] * l2e, c3 = coef[h * 4 + 3] * l2e;
        const float d = (float)t;
        lut[t] = (t <= 46) ? (((c3 * d + c2) * d + c1) * d + c0) : 0.f;
    }

    const int qrow0 = qt * 64 + w * 16;
    const u16* qp = Qg + ((size_t)bh * 640 + qrow0 + lr) * 64;
    const bf16x8 qa0 = *(const bf16x8*)(qp + lg * 8);
    const bf16x8 qa1 = *(const bf16x8*)(qp + 32 + lg * 8);

    float gi[4], gj[4];
#pragma unroll
    for (int r = 0; r < 4; ++r) {
        const int n = qrow0 + 4 * lg + r;
        if (n == 0) { gi[r] = 100.f; gj[r] = 0.f; }
        else {
            const int nm1 = n - 1;
            const int qi = nm1 / 24;
            gi[r] = (float)qi;
            gj[r] = (float)(nm1 - qi * 24);
        }
    }

    float M[4], L[4];
#pragma unroll
    for (int r = 0; r < 4; ++r) { M[r] = -3e38f; L[r] = 0.f; }
    f32x4 acco[4] = {};
    const float scale2 = 0.125f * 1.4426950408889634f;
    const int ch0 = ((lg ^ (lr & 7))) * 8;      // swizzled read chunk (elems)

    const u16* Ksb = Kg + (size_t)bh * 640 * 64;
    const u16* Vsb = Vtg + (size_t)bh * 64 * 640;
    const int pr0 = t >> 3, pc0 = t & 7;
    const int pr1 = (256 + t) >> 3, pc1 = (256 + t) & 7;
    const int kd0 = pr0 * 64 + ((pc0 ^ (pr0 & 7)) * 8);   // swizzled LDS offs
    const int kd1 = pr1 * 64 + ((pc1 ^ (pr1 & 7)) * 8);

    {   // prologue: tile 0 -> regs -> LDS buf 0
        uint4 k0 = *(const uint4*)(Ksb + pr0 * 64 + pc0 * 8);
        uint4 k1 = *(const uint4*)(Ksb + pr1 * 64 + pc1 * 8);
        uint4 v0 = *(const uint4*)(Vsb + (size_t)pr0 * 640 + pc0 * 8);
        uint4 v1 = *(const uint4*)(Vsb + (size_t)pr1 * 640 + pc1 * 8);
        *(uint4*)(&Kl[0][kd0]) = k0;
        *(uint4*)(&Kl[0][kd1]) = k1;
        *(uint4*)(&Vl[0][kd0]) = v0;
        *(uint4*)(&Vl[0][kd1]) = v1;
    }
    __syncthreads();
    int cur = 0;

    for (int kt = 0; kt < 9; ++kt) {
        // issue next K/V tile's loads early (tile kt+1, incl. tail tile 9)
        const u16* Ks = Ksb + (size_t)(kt + 1) * 64 * 64;
        const u16* Vs = Vsb + (size_t)(kt + 1) * 64;
        const uint4 nk0 = *(const uint4*)(Ks + pr0 * 64 + pc0 * 8);
        const uint4 nk1 = *(const uint4*)(Ks + pr1 * 64 + pc1 * 8);
        const uint4 nv0 = *(const uint4*)(Vs + (size_t)pr0 * 640 + pc0 * 8);
        const uint4 nv1 = *(const uint4*)(Vs + (size_t)pr1 * 640 + pc1 * 8);

        const u16* Kc = &Kl[cur][0];
        const u16* Vc = &Vl[cur][0];

        // S = Q K^T (full tile, no branches)
        f32x4 sac[4];
#pragma unroll
        for (int cb = 0; cb < 4; ++cb) {
            const int row = cb * 16 + lr;
            const bf16x8 kb0 = *(const bf16x8*)(Kc + row * 64 + ch0);
            const bf16x8 kb1 = *(const bf16x8*)(Kc + row * 64 + (ch0 ^ 32));
            f32x4 z = {};
            z = mfma16(qa0, kb0, z);
            sac[cb] = mfma16(qa1, kb1, z);
        }

        float s[4][4], tm[4];
#pragma unroll
        for (int r = 0; r < 4; ++r) tm[r] = -3e38f;
#pragma unroll
        for (int cb = 0; cb < 4; ++cb) {
            const int m = kt * 64 + cb * 16 + lr;
            float ci, cj;
            if (m == 0) { ci = 200.f; cj = 0.f; }
            else {
                const int mm1 = m - 1;
                const int pi = mm1 / 24;
                ci = (float)pi;
                cj = (float)(mm1 - pi * 24);
            }
#pragma unroll
            for (int r = 0; r < 4; ++r) {
                const float df = fabsf(gi[r] - ci) + fabsf(gj[r] - cj);
                const int idx = (int)df;
                const float v = fmaf(sac[cb][r], scale2, lut[idx]);
                s[cb][r] = v;
                tm[r] = fmaxf(tm[r], v);
            }
        }
#pragma unroll
        for (int r = 0; r < 4; ++r) tm[r] = dpp_max16(tm[r]);

        float over = tm[0] - M[0];
        over = fmaxf(over, tm[1] - M[1]);
        over = fmaxf(over, tm[2] - M[2]);
        over = fmaxf(over, tm[3] - M[3]);
        if (__any(over > 11.5f)) {
#pragma unroll
            for (int r = 0; r < 4; ++r) {
                const float Mn = fmaxf(M[r], tm[r]);
                const float a = fexp2(M[r] - Mn);
                L[r] *= a;
                acco[0][r] *= a; acco[1][r] *= a;
                acco[2][r] *= a; acco[3][r] *= a;
                M[r] = Mn;
            }
        }

        u16* pw = &Plds[w][0];
#pragma unroll
        for (int cb = 0; cb < 4; ++cb)
#pragma unroll
            for (int r = 0; r < 4; ++r) {
                const float p = fexp2(s[cb][r] - M[r]);
                L[r] += p;
                pw[(4 * lg + r) * 72 + cb * 16 + lr] = f2bf(p);
            }
        const bf16x8 pa0 = *(const bf16x8*)(pw + lr * 72 + lg * 8);
        const bf16x8 pa1 = *(const bf16x8*)(pw + lr * 72 + 32 + lg * 8);
#pragma unroll
        for (int f = 0; f < 4; ++f) {
            const int vrow = f * 16 + lr;
            const bf16x8 vb0 = *(const bf16x8*)(Vc + vrow * 64 + ch0);
            const bf16x8 vb1 = *(const bf16x8*)(Vc + vrow * 64 + (ch0 ^ 32));
            acco[f] = mfma16(pa0, vb0, acco[f]);
            acco[f] = mfma16(pa1, vb1, acco[f]);
        }

        // land prefetched tile into the OTHER buffer (no wave reads it this
        // iter -> no pre-store barrier needed; vmcnt wait implicit on data)
        *(uint4*)(&Kl[cur ^ 1][kd0]) = nk0;
        *(uint4*)(&Kl[cur ^ 1][kd1]) = nk1;
        *(uint4*)(&Vl[cur ^ 1][kd0]) = nv0;
        *(uint4*)(&Vl[cur ^ 1][kd1]) = nv1;
        __syncthreads();
        cur ^= 1;
    }

    {   // ---- peeled tail tile (kt=9): only key m=576 (cb=0, lr==0) valid ----
        const u16* Kc = &Kl[cur][0];
        const u16* Vc = &Vl[cur][0];
        const bf16x8 kb0 = *(const bf16x8*)(Kc + lr * 64 + ch0);
        const bf16x8 kb1 = *(const bf16x8*)(Kc + lr * 64 + (ch0 ^ 32));
        f32x4 z = {};
        z = mfma16(qa0, kb0, z);
        const f32x4 sac0 = mfma16(qa1, kb1, z);

        // key 576 coords: (23,23)
        float s0[4], tm[4];
#pragma unroll
        for (int r = 0; r < 4; ++r) {
            const float df = fabsf(gi[r] - 23.f) + fabsf(gj[r] - 23.f);
            float v = fmaf(sac0[r], scale2, lut[(int)df]);
            v = (lr == 0) ? v : -1e30f;
            s0[r] = v;
            tm[r] = dpp_max16(v);
        }
        float over = tm[0] - M[0];
        over = fmaxf(over, tm[1] - M[1]);
        over = fmaxf(over, tm[2] - M[2]);
        over = fmaxf(over, tm[3] - M[3]);
        if (__any(over > 11.5f)) {
#pragma unroll
            for (int r = 0; r < 4; ++r) {
                const float Mn = fmaxf(M[r], tm[r]);
                const float a = fexp2(M[r] - Mn);
                L[r] *= a;
                acco[0][r] *= a; acco[1][r] *= a;
                acco[2][r] *= a; acco[3][r] *= a;
                M[r] = Mn;
            }
        }
        u16* pw = &Plds[w][0];
#pragma unroll
        for (int cb = 0; cb < 4; ++cb)
#pragma unroll
            for (int r = 0; r < 4; ++r) {
                const float p = (cb == 0) ? fexp2(s0[r] - M[r]) : 0.f;
                L[r] += p;
                pw[(4 * lg + r) * 72 + cb * 16 + lr] = f2bf(p);
            }
        const bf16x8 pa0 = *(const bf16x8*)(pw + lr * 72 + lg * 8);
#pragma unroll
        for (int f = 0; f < 4; ++f) {
            const int vrow = f * 16 + lr;
            const bf16x8 vb0 = *(const bf16x8*)(Vc + vrow * 64 + ch0);
            acco[f] = mfma16(pa0, vb0, acco[f]);
        }
    }

    float inv[4];
#pragma unroll
    for (int r = 0; r < 4; ++r) inv[r] = __builtin_amdgcn_rcpf(dpp_sum16(L[r]));
#pragma unroll
    for (int f = 0; f < 4; ++f)
#pragma unroll
        for (int r = 0; r < 4; ++r) {
            const int n = qrow0 + 4 * lg + r;     // <= 575, always valid
            Og[((size_t)b * 577 + n) * 768 + h * 64 + f * 16 + lr] =
                f2bf(acco[f][r] * inv[r]);
        }
}

// ---------------- attention for the single leftover row n=576 ----------------
__launch_bounds__(256)
__global__ void k_attn_last(const u16* __restrict__ Qg, const u16* __restrict__ Kg,
                            const u16* __restrict__ Vtg, const float* __restrict__ coef,
                            u16* __restrict__ Og) {
    const int bh = blockIdx.x;
    const int b = bh / 12, h = bh - b * 12;
    const int t = threadIdx.x;
    const int lane = t & 63, w = t >> 6;
    __shared__ float qs[64];
    __shared__ float ps[640];
    __shared__ float red[4];
    __shared__ float opart[4][64];
    const float l2e = 1.4426950408889634f;
    const float c0 = coef[h * 4 + 0] * l2e, c1 = coef[h * 4 + 1] * l2e,
                c2 = coef[h * 4 + 2] * l2e, c3 = coef[h * 4 + 3] * l2e;
    const float scale2 = 0.125f * l2e;

    if (t < 64) qs[t] = bf2f(Qg[((size_t)bh * 640 + 576) * 64 + t]);
    __syncthreads();

    float sv[3];
#pragma unroll
    for (int u = 0; u < 3; ++u) {
        const int k = t + u * 256;
        float s = -3e38f;
        if (k < 577) {
            const u16* kp = Kg + ((size_t)bh * 640 + k) * 64;
            float acc = 0.f;
            for (int j = 0; j < 64; ++j) acc += qs[j] * bf2f(kp[j]);
            float rv = 0.f;
            if (k >= 1) {
                const int km1 = k - 1;
                const int ki = km1 / 24;
                const float d = fabsf(23.f - (float)ki) + fabsf(23.f - (float)(km1 - ki * 24));
                rv = ((c3 * d + c2) * d + c1) * d + c0;
            }
            s = fmaf(acc, scale2, rv);
        }
        sv[u] = s;
    }
    float v = fmaxf(fmaxf(sv[0], sv[1]), sv[2]);
    v = fmaxf(v, __shfl_xor(v, 1));  v = fmaxf(v, __shfl_xor(v, 2));
    v = fmaxf(v, __shfl_xor(v, 4));  v = fmaxf(v, __shfl_xor(v, 8));
    v = fmaxf(v, __shfl_xor(v, 16)); v = fmaxf(v, __shfl_xor(v, 32));
    if (lane == 0) red[w] = v;
    __syncthreads();
    const float Mx = fmaxf(fmaxf(red[0], red[1]), fmaxf(red[2], red[3]));

    float lsum = 0.f;
#pragma unroll
    for (int u = 0; u < 3; ++u) {
        const int k = t + u * 256;
        const float p = (k < 577) ? fexp2(sv[u] - Mx) : 0.f;
        if (k < 640) ps[k] = p;
        lsum += p;
    }
    lsum += __shfl_xor(lsum, 1);  lsum += __shfl_xor(lsum, 2);
    lsum += __shfl_xor(lsum, 4);  lsum += __shfl_xor(lsum, 8);
    lsum += __shfl_xor(lsum, 16); lsum += __shfl_xor(lsum, 32);
    __syncthreads();
    if (lane == 0) red[w] = lsum;
    __syncthreads();
    const float Lx = red[0] + red[1] + red[2] + red[3];

    const int d = t & 63, qd = t >> 6;
    const u16* vp = Vtg + ((size_t)bh * 64 + d) * 640;
    float o = 0.f;
    for (int k = qd * 160; k < qd * 160 + 160; ++k) o += ps[k] * bf2f(vp[k]);
    opart[qd][d] = o;
    __syncthreads();
    if (t < 64) {
        const float oo = (opart[0][t] + opart[1][t] + opart[2][t] + opart[3][t]) / Lx;
        Og[((size_t)b * 577 + 576) * 768 + h * 64 + t] = f2bf(oo);
    }
}

// ---------------- launch ----------------
extern "C" void kernel_launch(void* const* d_in, const int* in_sizes, int n_in,
                              void* d_out, int out_size, void* d_ws, size_t ws_size,
                              hipStream_t stream) {
    const float* x      = (const float*)d_in[0];
    const float* W_qkv  = (const float*)d_in[1];
    const float* W_proj = (const float*)d_in[2];
    const float* b_proj = (const float*)d_in[3];
    const float* coef   = (const float*)d_in[4];
    float* out = (float*)d_out;
    char* ws = (char*)d_ws;

    // ws layout with lifetime aliasing (66.1 MB total):
    //   xb : live prep..gemm0  |  Og : live attn..gemm1 (ALIASES xb)
    u16* xb   = (u16*)(ws + 0);                        // 14,180,352
    u16* Og   = (u16*)(ws + 0);                        // aliases xb
    u16* wqkv = (u16*)(ws + 14180352);                 //  3,538,944 (absorbs OOB)
    u16* wprj = (u16*)(ws + 17719296);                 //  1,179,648
    u16* Qg   = (u16*)(ws + 18898944);                 // 15,728,640
    u16* Kg   = (u16*)(ws + 34627584);                 // 15,728,640
    u16* Vtg  = (u16*)(ws + 50356224);                 // 15,728,640 -> 66,084,864
    // No Vtg memset: pad keys get P = exp2(-1e30-M) = 0 exactly; 0*finite = 0.

    k_prep<<<2048, 256, 0, stream>>>(x, W_qkv, W_proj, xb, wqkv, wprj);

    k_gemm<0, 18><<<18 * 73, 256, 0, stream>>>(xb, wqkv, Qg, Kg, Vtg,
                                               nullptr, nullptr);
    k_attn<<<dim3(9, 192), 256, 0, stream>>>(Qg, Kg, Vtg, coef, Og);
    k_attn_last<<<192, 256, 0, stream>>>(Qg, Kg, Vtg, coef, Og);
    k_gemm<1, 6><<<6 * 73, 256, 0, stream>>>(Og, wprj, nullptr, nullptr,
                                             nullptr, out, b_proj);
}

// Round 9
// 171.855 us; speedup vs baseline: 1.2046x; 1.0689x over previous
//
#include <hip/hip_runtime.h>

// PolyRPE attention, MI355X gfx950.
// prep (cvt + LDS-tiled transposes) -> QKV GEMM (128x128, BK=32, 4-buffer
// gl_lds, dist-3, vmcnt(8), T2 swizzle, T1 XCD grid) -> fused flash attention
// (4 blocks/CU: P overlaid on dead V buffer, wave-owned V staging, 1 barrier/
// tile, XCD bh-major grid, setprio) -> proj GEMM.
//
// Dims: B=16, N=577 (pad 640), C=768, h=12, d=64, K=768, 3C=2304.

using u16 = unsigned short;
using u32 = unsigned int;

typedef __bf16 bf16x8 __attribute__((ext_vector_type(8)));
typedef float f32x4 __attribute__((ext_vector_type(4)));

__device__ inline u16 f2bf(float f) {
    u32 u = __builtin_bit_cast(u32, f);
    u32 r = u + 0x7fffu + ((u >> 16) & 1u);   // RNE
    return (u16)(r >> 16);
}
__device__ inline float bf2f(u16 x) {
    return __builtin_bit_cast(float, (u32)x << 16);
}

__device__ inline f32x4 mfma16(bf16x8 a, bf16x8 b, f32x4 c) {
    return __builtin_amdgcn_mfma_f32_16x16x32_bf16(a, b, c, 0, 0, 0);
}

__device__ inline float fexp2(float x) { return __builtin_amdgcn_exp2f(x); }

// bijective XCD chunk remap (m204)
__device__ inline int xcd_remap(int bid, int nwg) {
    const int q = nwg >> 3, r = nwg & 7;
    const int xcd = bid & 7, idx = bid >> 3;
    return (xcd < r ? xcd * (q + 1) : r * (q + 1) + (xcd - r) * q) + idx;
}

// 16-lane (DPP-row) reductions.
__device__ inline float dpp_max16(float v) {
    int x;
    x = __builtin_amdgcn_update_dpp(0, __builtin_bit_cast(int, v), 0xB1, 0xF, 0xF, true);
    v = fmaxf(v, __builtin_bit_cast(float, x));
    x = __builtin_amdgcn_update_dpp(0, __builtin_bit_cast(int, v), 0x4E, 0xF, 0xF, true);
    v = fmaxf(v, __builtin_bit_cast(float, x));
    x = __builtin_amdgcn_update_dpp(0, __builtin_bit_cast(int, v), 0x124, 0xF, 0xF, true);
    v = fmaxf(v, __builtin_bit_cast(float, x));
    x = __builtin_amdgcn_update_dpp(0, __builtin_bit_cast(int, v), 0x128, 0xF, 0xF, true);
    v = fmaxf(v, __builtin_bit_cast(float, x));
    return v;
}
__device__ inline float dpp_sum16(float v) {
    int x;
    x = __builtin_amdgcn_update_dpp(0, __builtin_bit_cast(int, v), 0xB1, 0xF, 0xF, true);
    v += __builtin_bit_cast(float, x);
    x = __builtin_amdgcn_update_dpp(0, __builtin_bit_cast(int, v), 0x4E, 0xF, 0xF, true);
    v += __builtin_bit_cast(float, x);
    x = __builtin_amdgcn_update_dpp(0, __builtin_bit_cast(int, v), 0x124, 0xF, 0xF, true);
    v += __builtin_bit_cast(float, x);
    x = __builtin_amdgcn_update_dpp(0, __builtin_bit_cast(int, v), 0x128, 0xF, 0xF, true);
    v += __builtin_bit_cast(float, x);
    return v;
}

#define GLOAD_LDS16(g, l)                                                          \
    __builtin_amdgcn_global_load_lds((const __attribute__((address_space(1))) u32*)(g), \
                                     (__attribute__((address_space(3))) u32*)(l), 16, 0, 0)

#define BAR()    asm volatile("s_barrier" ::: "memory")
#define WAITV8() asm volatile("s_waitcnt vmcnt(8)" ::: "memory")
#define WAITV4() asm volatile("s_waitcnt vmcnt(4)" ::: "memory")
#define WAITV0() asm volatile("s_waitcnt vmcnt(0)" ::: "memory")

// ---------------- prep ----------------
// blocks 0..575: LDS-tiled 64x64 transposes (432 wqkv + 144 wprj)
// blocks 576..2047: x fp32 -> bf16 (vectorized)
__global__ void k_prep(const float* __restrict__ x, const float* __restrict__ Wq,
                       const float* __restrict__ Wp, u16* __restrict__ xb,
                       u16* __restrict__ wqkv, u16* __restrict__ wprj) {
    const int bid = blockIdx.x;
    const int t = threadIdx.x;
    if (bid < 576) {
        __shared__ float tile[64][65];
        const float* src;
        u16* dst;
        int C, rt, ct;
        if (bid < 432) { src = Wq; dst = wqkv; C = 2304; rt = bid / 36; ct = bid % 36; }
        else { const int b2 = bid - 432; src = Wp; dst = wprj; C = 768; rt = b2 / 12; ct = b2 % 12; }
        const int row0 = rt * 64, col0 = ct * 64;
#pragma unroll
        for (int it = 0; it < 4; ++it) {
            const int row = it * 16 + (t >> 4);
            const float4 v = *(const float4*)&src[(size_t)(row0 + row) * C + col0 + (t & 15) * 4];
            tile[row][(t & 15) * 4 + 0] = v.x;
            tile[row][(t & 15) * 4 + 1] = v.y;
            tile[row][(t & 15) * 4 + 2] = v.z;
            tile[row][(t & 15) * 4 + 3] = v.w;
        }
        __syncthreads();
#pragma unroll
        for (int it = 0; it < 4; ++it) {
            const int oc = it * 16 + (t >> 4);     // input col = output row
            const int orr = (t & 15) * 4;          // input row = output col
            ushort4 o;
            o.x = f2bf(tile[orr + 0][oc]);
            o.y = f2bf(tile[orr + 1][oc]);
            o.z = f2bf(tile[orr + 2][oc]);
            o.w = f2bf(tile[orr + 3][oc]);
            *(ushort4*)&dst[(size_t)(col0 + oc) * 768 + row0 + orr] = o;
        }
    } else {
        const int n4 = 9232 * 768 / 4;
        const int stride = (2048 - 576) * 256;
        for (int i = (bid - 576) * 256 + t; i < n4; i += stride) {
            float4 v = ((const float4*)x)[i];
            ushort4 o;
            o.x = f2bf(v.x); o.y = f2bf(v.y); o.z = f2bf(v.z); o.w = f2bf(v.w);
            ((ushort4*)xb)[i] = o;
        }
    }
}

// ---------------- GEMM (unchanged from round 8; 76.4 us) --------------------
__device__ inline void stageAB(const u16* __restrict__ Ag, const u16* __restrict__ Bg,
                               u16* L, int t) {
#pragma unroll
    for (int c = 0; c < 2; ++c) {
        const int p = c * 256 + t;
        const int row = p >> 2, ch = p & 3;
        const int src = row * 768 + ((ch ^ ((row >> 1) & 3)) * 8);
        GLOAD_LDS16(Ag + src, L + p * 8);
        GLOAD_LDS16(Bg + src, L + 4096 + p * 8);
    }
}
__device__ inline bf16x8 ldfrag32(const u16* base, int row, int slot) {
    return *(const bf16x8*)(base + row * 32 + ((slot ^ ((row >> 1) & 3)) * 8));
}

template <int MODE, int NB>
__launch_bounds__(256, 2)
__global__ void k_gemm(const u16* __restrict__ A, const u16* __restrict__ Bw,
                       u16* __restrict__ q_out, u16* __restrict__ k_out,
                       u16* __restrict__ v_out,
                       float* __restrict__ f_out, const float* __restrict__ bias) {
    constexpr int NT = 24;                    // 768/32
    constexpr int M = 9232;
    const int wgid = xcd_remap(blockIdx.x, gridDim.x);
    const int mbase = (wgid / NB) * 128;
    const int nbase = (wgid - (wgid / NB) * NB) * 128;
    __shared__ alignas(16) u16 lds[4][8192];  // 64 KB -> 2 blocks/CU
    const int t = threadIdx.x;
    const int lane = t & 63, w = t >> 6;
    const int lr = lane & 15, lg = lane >> 4;
    const int wrow = (w >> 1) * 64, wcol = (w & 1) * 64;
    const u16* Ag = A + (size_t)mbase * 768;
    const u16* Bg = Bw + (size_t)nbase * 768;
    f32x4 acc[4][4] = {};

    stageAB(Ag, Bg, &lds[0][0], t);
    stageAB(Ag + 32, Bg + 32, &lds[1][0], t);
    stageAB(Ag + 64, Bg + 64, &lds[2][0], t);
    WAITV8();           // tile 0 resident; tiles 1,2 in flight
    BAR();

    for (int kt = 0; kt < NT; ++kt) {
        const u16* Lc = &lds[kt & 3][0];
        if (kt + 3 < NT)
            stageAB(Ag + (kt + 3) * 32, Bg + (kt + 3) * 32, &lds[(kt + 3) & 3][0], t);
        bf16x8 af[4], bv[4];
#pragma unroll
        for (int i = 0; i < 4; ++i)
            af[i] = ldfrag32(Lc, wrow + i * 16 + lr, lg);
#pragma unroll
        for (int j = 0; j < 4; ++j)
            bv[j] = ldfrag32(Lc + 4096, wcol + j * 16 + lr, lg);
        __builtin_amdgcn_s_setprio(1);
#pragma unroll
        for (int i = 0; i < 4; ++i)
#pragma unroll
            for (int j = 0; j < 4; ++j)
                acc[i][j] = mfma16(af[i], bv[j], acc[i][j]);
        __builtin_amdgcn_s_setprio(0);
        if (kt + 1 < NT) {
            if (kt < NT - 3)       { WAITV8(); }
            else if (kt == NT - 3) { WAITV4(); }
            else                   { WAITV0(); }
            BAR();
        }
    }

#pragma unroll
    for (int i = 0; i < 4; ++i) {
#pragma unroll
        for (int j = 0; j < 4; ++j) {
            const int col = nbase + wcol + j * 16 + lr;
#pragma unroll
            for (int r = 0; r < 4; ++r) {
                const int row = mbase + wrow + i * 16 + 4 * lg + r;
                if (row < M) {
                    if (MODE == 0) {
                        const int bb = row / 577;
                        const int nn = row - bb * 577;
                        const int tt = col / 768;
                        const int rem = col - tt * 768;
                        const int hh = rem >> 6, dd = rem & 63;
                        const size_t bh = (size_t)bb * 12 + hh;
                        const u16 val = f2bf(acc[i][j][r]);
                        if (tt == 0)      q_out[(bh * 640 + nn) * 64 + dd] = val;
                        else if (tt == 1) k_out[(bh * 640 + nn) * 64 + dd] = val;
                        else              v_out[(bh * 64 + dd) * 640 + nn] = val;
                    } else {
                        f_out[(size_t)row * 768 + col] = acc[i][j][r] + bias[col];
                    }
                }
            }
        }
    }
}

// ---------------- fused attention (q rows 0..575) ----------------
// 33 KB LDS -> 4 blocks/CU. P overlays Vl[cur^1] (dead V buffer); V staging
// rows are wave-owned so post-PV stores only touch the wave's consumed P.
__launch_bounds__(256, 4)
__global__ void k_attn(const u16* __restrict__ Qg, const u16* __restrict__ Kg,
                       const u16* __restrict__ Vtg, const float* __restrict__ coef,
                       u16* __restrict__ Og) {
    const int wgid = xcd_remap(blockIdx.x, gridDim.x);   // 1728 = 8*216 exact
    const int bh = wgid / 9;            // consecutive wgids share bh (XCD-local K/V)
    const int qt = wgid - bh * 9;       // 0..8
    const int b = bh / 12, h = bh - b * 12;
    const int t = threadIdx.x;
    const int lane = t & 63, w = t >> 6;
    const int lr = lane & 15, lg = lane >> 4;
    __shared__ alignas(16) u16 Kl[2][4096];
    __shared__ alignas(16) u16 Vl[2][4096];
    __shared__ float lut[48];

    {   // LUT: poly(dist)*log2e for dist<=46; lut[47]=0 catches CLS sentinels
        const float l2e = 1.4426950408889634f;
        const float c0 = coef[h * 4 + 0] * l2e, c1 = coef[h * 4 + 1] * l2e,
                    c2 = coef[h * 4 + 2] * l2e, c3 = coef[h * 4 + 3] * l2e;
        if (t < 48) {
            const float d = (float)t;
            lut[t] = (t <= 46) ? (((c3 * d + c2) * d + c1) * d + c0) : 0.f;
        }
    }

    const int qrow0 = qt * 64 + w * 16;
    const u16* qp = Qg + ((size_t)bh * 640 + qrow0 + lr) * 64;
    const bf16x8 qa0 = *(const bf16x8*)(qp + lg * 8);
    const bf16x8 qa1 = *(const bf16x8*)(qp + 32 + lg * 8);

    float gi[4], gj[4];
#pragma unroll
    for (int r = 0; r < 4; ++r) {
        const int n = qrow0 + 4 * lg + r;
        if (n == 0) { gi[r] = 100.f; gj[r] = 0.f; }
        else {
            const int nm1 = n - 1;
            const int qi = nm1 / 24;
            gi[r] = (float)qi;
            gj[r] = (float)(nm1 - qi * 24);
        }
    }

    float M[4], L[4];
#pragma unroll
    for (int r = 0; r < 4; ++r) { M[r] = -3e38f; L[r] = 0.f; }
    f32x4 acco[4] = {};
    const float scale2 = 0.125f * 1.4426950408889634f;
    const int ch0 = ((lg ^ (lr & 7))) * 8;      // swizzled read chunk (elems)

    const u16* Ksb = Kg + (size_t)bh * 640 * 64;
    const u16* Vsb = Vtg + (size_t)bh * 64 * 640;
    // K staging: rows t>>3 (any order; Kl[cur^1] unread this tile)
    const int pr0 = t >> 3, pc0 = t & 7;
    const int pr1 = (256 + t) >> 3, pc1 = (256 + t) & 7;
    const int kd0 = pr0 * 64 + ((pc0 ^ (pr0 & 7)) * 8);
    const int kd1 = pr1 * 64 + ((pc1 ^ (pr1 & 7)) * 8);
    // V staging: wave-owned rows (wave w -> rows 16w..16w+15)
    const int vr0 = 16 * w + (lane >> 3), vc = lane & 7;
    const int vr1 = vr0 + 8;
    const int vd0 = vr0 * 64 + ((vc ^ (vr0 & 7)) * 8);
    const int vd1 = vr1 * 64 + ((vc ^ (vr1 & 7)) * 8);

    {   // prologue: tile 0 -> regs -> LDS buf 0
        uint4 k0 = *(const uint4*)(Ksb + pr0 * 64 + pc0 * 8);
        uint4 k1 = *(const uint4*)(Ksb + pr1 * 64 + pc1 * 8);
        uint4 v0 = *(const uint4*)(Vsb + (size_t)vr0 * 640 + vc * 8);
        uint4 v1 = *(const uint4*)(Vsb + (size_t)vr1 * 640 + vc * 8);
        *(uint4*)(&Kl[0][kd0]) = k0;
        *(uint4*)(&Kl[0][kd1]) = k1;
        *(uint4*)(&Vl[0][vd0]) = v0;
        *(uint4*)(&Vl[0][vd1]) = v1;
    }
    __syncthreads();
    int cur = 0;

    for (int kt = 0; kt < 9; ++kt) {
        // issue next K/V tile's loads early (incl. tail tile 9)
        const u16* Ks = Ksb + (size_t)(kt + 1) * 64 * 64;
        const u16* Vs = Vsb + (size_t)(kt + 1) * 64;
        const uint4 nk0 = *(const uint4*)(Ks + pr0 * 64 + pc0 * 8);
        const uint4 nk1 = *(const uint4*)(Ks + pr1 * 64 + pc1 * 8);
        const uint4 nv0 = *(const uint4*)(Vs + (size_t)vr0 * 640 + vc * 8);
        const uint4 nv1 = *(const uint4*)(Vs + (size_t)vr1 * 640 + vc * 8);

        const u16* Kc = &Kl[cur][0];
        const u16* Vc = &Vl[cur][0];
        u16* pw = &Vl[cur ^ 1][w * 1024];    // P overlay: wave-owned 16x64

        // S = Q K^T
        f32x4 sac[4];
        __builtin_amdgcn_s_setprio(1);
#pragma unroll
        for (int cb = 0; cb < 4; ++cb) {
            const int row = cb * 16 + lr;
            const bf16x8 kb0 = *(const bf16x8*)(Kc + row * 64 + ch0);
            const bf16x8 kb1 = *(const bf16x8*)(Kc + row * 64 + (ch0 ^ 32));
            f32x4 z = {};
            z = mfma16(qa0, kb0, z);
            sac[cb] = mfma16(qa1, kb1, z);
        }
        __builtin_amdgcn_s_setprio(0);

        float s[4][4], tm[4];
#pragma unroll
        for (int r = 0; r < 4; ++r) tm[r] = -3e38f;
#pragma unroll
        for (int cb = 0; cb < 4; ++cb) {
            const int m = kt * 64 + cb * 16 + lr;
            float ci, cj;
            if (m == 0) { ci = 200.f; cj = 0.f; }
            else {
                const int mm1 = m - 1;
                const int pi = mm1 / 24;
                ci = (float)pi;
                cj = (float)(mm1 - pi * 24);
            }
#pragma unroll
            for (int r = 0; r < 4; ++r) {
                const float df = fabsf(gi[r] - ci) + fabsf(gj[r] - cj);
                const int idx = min((int)df, 47);
                const float v = fmaf(sac[cb][r], scale2, lut[idx]);
                s[cb][r] = v;
                tm[r] = fmaxf(tm[r], v);
            }
        }
#pragma unroll
        for (int r = 0; r < 4; ++r) tm[r] = dpp_max16(tm[r]);

        float over = tm[0] - M[0];
        over = fmaxf(over, tm[1] - M[1]);
        over = fmaxf(over, tm[2] - M[2]);
        over = fmaxf(over, tm[3] - M[3]);
        if (__any(over > 11.5f)) {
#pragma unroll
            for (int r = 0; r < 4; ++r) {
                const float Mn = fmaxf(M[r], tm[r]);
                const float a = fexp2(M[r] - Mn);
                L[r] *= a;
                acco[0][r] *= a; acco[1][r] *= a;
                acco[2][r] *= a; acco[3][r] *= a;
                M[r] = Mn;
            }
        }

        // P -> overlay (swizzled): row'=4lg+r, chunk=2cb+(lr>>3), elem=lr&7
#pragma unroll
        for (int cb = 0; cb < 4; ++cb)
#pragma unroll
            for (int r = 0; r < 4; ++r) {
                const float p = fexp2(s[cb][r] - M[r]);
                L[r] += p;
                const int rw = 4 * lg + r;
                pw[rw * 64 + (((2 * cb + (lr >> 3)) ^ (rw & 7)) * 8) + (lr & 7)] = f2bf(p);
            }
        const bf16x8 pa0 = *(const bf16x8*)(pw + lr * 64 + ch0);
        const bf16x8 pa1 = *(const bf16x8*)(pw + lr * 64 + (ch0 ^ 32));
        __builtin_amdgcn_s_setprio(1);
#pragma unroll
        for (int f = 0; f < 4; ++f) {
            const int vrow = f * 16 + lr;
            const bf16x8 vb0 = *(const bf16x8*)(Vc + vrow * 64 + ch0);
            const bf16x8 vb1 = *(const bf16x8*)(Vc + vrow * 64 + (ch0 ^ 32));
            acco[f] = mfma16(pa0, vb0, acco[f]);
            acco[f] = mfma16(pa1, vb1, acco[f]);
        }
        __builtin_amdgcn_s_setprio(0);

        // land prefetched tile: K anywhere in Kl[cur^1] (unread); V only into
        // this wave's own rows (its P was consumed above; per-wave DS order)
        *(uint4*)(&Kl[cur ^ 1][kd0]) = nk0;
        *(uint4*)(&Kl[cur ^ 1][kd1]) = nk1;
        *(uint4*)(&Vl[cur ^ 1][vd0]) = nv0;
        *(uint4*)(&Vl[cur ^ 1][vd1]) = nv1;
        __syncthreads();
        cur ^= 1;
    }

    {   // ---- peeled tail tile (kt=9): only key m=576 (cb=0, lr==0) valid ----
        const u16* Kc = &Kl[cur][0];
        const u16* Vc = &Vl[cur][0];
        u16* pw = &Vl[cur ^ 1][w * 1024];
        const bf16x8 kb0 = *(const bf16x8*)(Kc + lr * 64 + ch0);
        const bf16x8 kb1 = *(const bf16x8*)(Kc + lr * 64 + (ch0 ^ 32));
        f32x4 z = {};
        z = mfma16(qa0, kb0, z);
        const f32x4 sac0 = mfma16(qa1, kb1, z);

        float s0[4], tm[4];
#pragma unroll
        for (int r = 0; r < 4; ++r) {
            const float df = fabsf(gi[r] - 23.f) + fabsf(gj[r] - 23.f);
            float v = fmaf(sac0[r], scale2, lut[min((int)df, 47)]);
            v = (lr == 0) ? v : -1e30f;
            s0[r] = v;
            tm[r] = dpp_max16(v);
        }
        float over = tm[0] - M[0];
        over = fmaxf(over, tm[1] - M[1]);
        over = fmaxf(over, tm[2] - M[2]);
        over = fmaxf(over, tm[3] - M[3]);
        if (__any(over > 11.5f)) {
#pragma unroll
            for (int r = 0; r < 4; ++r) {
                const float Mn = fmaxf(M[r], tm[r]);
                const float a = fexp2(M[r] - Mn);
                L[r] *= a;
                acco[0][r] *= a; acco[1][r] *= a;
                acco[2][r] *= a; acco[3][r] *= a;
                M[r] = Mn;
            }
        }
#pragma unroll
        for (int cb = 0; cb < 4; ++cb)
#pragma unroll
            for (int r = 0; r < 4; ++r) {
                const float p = (cb == 0) ? fexp2(s0[r] - M[r]) : 0.f;
                L[r] += p;
                const int rw = 4 * lg + r;
                pw[rw * 64 + (((2 * cb + (lr >> 3)) ^ (rw & 7)) * 8) + (lr & 7)] = f2bf(p);
            }
        const bf16x8 pa0 = *(const bf16x8*)(pw + lr * 64 + ch0);
#pragma unroll
        for (int f = 0; f < 4; ++f) {
            const int vrow = f * 16 + lr;
            const bf16x8 vb0 = *(const bf16x8*)(Vc + vrow * 64 + ch0);
            acco[f] = mfma16(pa0, vb0, acco[f]);
        }
    }

    float inv[4];
#pragma unroll
    for (int r = 0; r < 4; ++r) inv[r] = __builtin_amdgcn_rcpf(dpp_sum16(L[r]));
#pragma unroll
    for (int f = 0; f < 4; ++f)
#pragma unroll
        for (int r = 0; r < 4; ++r) {
            const int n = qrow0 + 4 * lg + r;     // <= 575, always valid
            Og[((size_t)b * 577 + n) * 768 + h * 64 + f * 16 + lr] =
                f2bf(acco[f][r] * inv[r]);
        }
}

// ---------------- attention for the single leftover row n=576 ----------------
__launch_bounds__(256)
__global__ void k_attn_last(const u16* __restrict__ Qg, const u16* __restrict__ Kg,
                            const u16* __restrict__ Vtg, const float* __restrict__ coef,
                            u16* __restrict__ Og) {
    const int bh = blockIdx.x;
    const int b = bh / 12, h = bh - b * 12;
    const int t = threadIdx.x;
    const int lane = t & 63, w = t >> 6;
    __shared__ float qs[64];
    __shared__ float ps[640];
    __shared__ float red[4];
    __shared__ float opart[4][64];
    const float l2e = 1.4426950408889634f;
    const float c0 = coef[h * 4 + 0] * l2e, c1 = coef[h * 4 + 1] * l2e,
                c2 = coef[h * 4 + 2] * l2e, c3 = coef[h * 4 + 3] * l2e;
    const float scale2 = 0.125f * l2e;

    if (t < 64) qs[t] = bf2f(Qg[((size_t)bh * 640 + 576) * 64 + t]);
    __syncthreads();

    float sv[3];
#pragma unroll
    for (int u = 0; u < 3; ++u) {
        const int k = t + u * 256;
        float s = -3e38f;
        if (k < 577) {
            const u16* kp = Kg + ((size_t)bh * 640 + k) * 64;
            float acc = 0.f;
            for (int j = 0; j < 64; ++j) acc += qs[j] * bf2f(kp[j]);
            float rv = 0.f;
            if (k >= 1) {
                const int km1 = k - 1;
                const int ki = km1 / 24;
                const float d = fabsf(23.f - (float)ki) + fabsf(23.f - (float)(km1 - ki * 24));
                rv = ((c3 * d + c2) * d + c1) * d + c0;
            }
            s = fmaf(acc, scale2, rv);
        }
        sv[u] = s;
    }
    float v = fmaxf(fmaxf(sv[0], sv[1]), sv[2]);
    v = fmaxf(v, __shfl_xor(v, 1));  v = fmaxf(v, __shfl_xor(v, 2));
    v = fmaxf(v, __shfl_xor(v, 4));  v = fmaxf(v, __shfl_xor(v, 8));
    v = fmaxf(v, __shfl_xor(v, 16)); v = fmaxf(v, __shfl_xor(v, 32));
    if (lane == 0) red[w] = v;
    __syncthreads();
    const float Mx = fmaxf(fmaxf(red[0], red[1]), fmaxf(red[2], red[3]));

    float lsum = 0.f;
#pragma unroll
    for (int u = 0; u < 3; ++u) {
        const int k = t + u * 256;
        const float p = (k < 577) ? fexp2(sv[u] - Mx) : 0.f;
        if (k < 640) ps[k] = p;
        lsum += p;
    }
    lsum += __shfl_xor(lsum, 1);  lsum += __shfl_xor(lsum, 2);
    lsum += __shfl_xor(lsum, 4);  lsum += __shfl_xor(lsum, 8);
    lsum += __shfl_xor(lsum, 16); lsum += __shfl_xor(lsum, 32);
    __syncthreads();
    if (lane == 0) red[w] = lsum;
    __syncthreads();
    const float Lx = red[0] + red[1] + red[2] + red[3];

    const int d = t & 63, qd = t >> 6;
    const u16* vp = Vtg + ((size_t)bh * 64 + d) * 640;
    float o = 0.f;
    for (int k = qd * 160; k < qd * 160 + 160; ++k) o += ps[k] * bf2f(vp[k]);
    opart[qd][d] = o;
    __syncthreads();
    if (t < 64) {
        const float oo = (opart[0][t] + opart[1][t] + opart[2][t] + opart[3][t]) / Lx;
        Og[((size_t)b * 577 + 576) * 768 + h * 64 + t] = f2bf(oo);
    }
}

// ---------------- launch ----------------
extern "C" void kernel_launch(void* const* d_in, const int* in_sizes, int n_in,
                              void* d_out, int out_size, void* d_ws, size_t ws_size,
                              hipStream_t stream) {
    const float* x      = (const float*)d_in[0];
    const float* W_qkv  = (const float*)d_in[1];
    const float* W_proj = (const float*)d_in[2];
    const float* b_proj = (const float*)d_in[3];
    const float* coef   = (const float*)d_in[4];
    float* out = (float*)d_out;
    char* ws = (char*)d_ws;

    // ws layout with lifetime aliasing (66.1 MB total):
    //   xb : live prep..gemm0  |  Og : live attn..gemm1 (ALIASES xb)
    u16* xb   = (u16*)(ws + 0);                        // 14,180,352
    u16* Og   = (u16*)(ws + 0);                        // aliases xb
    u16* wqkv = (u16*)(ws + 14180352);                 //  3,538,944 (absorbs OOB)
    u16* wprj = (u16*)(ws + 17719296);                 //  1,179,648
    u16* Qg   = (u16*)(ws + 18898944);                 // 15,728,640
    u16* Kg   = (u16*)(ws + 34627584);                 // 15,728,640
    u16* Vtg  = (u16*)(ws + 50356224);                 // 15,728,640 -> 66,084,864
    // No Vtg memset: pad keys get P = exp2(-1e30-M) = 0 exactly; 0*finite = 0.

    k_prep<<<2048, 256, 0, stream>>>(x, W_qkv, W_proj, xb, wqkv, wprj);

    k_gemm<0, 18><<<18 * 73, 256, 0, stream>>>(xb, wqkv, Qg, Kg, Vtg,
                                               nullptr, nullptr);
    k_attn<<<1728, 256, 0, stream>>>(Qg, Kg, Vtg, coef, Og);
    k_attn_last<<<192, 256, 0, stream>>>(Qg, Kg, Vtg, coef, Og);
    k_gemm<1, 6><<<6 * 73, 256, 0, stream>>>(Og, wprj, nullptr, nullptr,
                                             nullptr, out, b_proj);
}